// Round 2
// 1732.007 us; speedup vs baseline: 1.7900x; 1.7900x over previous
//
#include <hip/hip_runtime.h>

// ---------------------------------------------------------------------------
// TransformerBlock: B=2, L=2048, D=2048, H=16, HD=128, FF=8192.
// Dual-dtype (runtime-detected): pipelines instantiated for DT=0 (f32 I/O)
// and DT=1 (bf16 I/O); a detector kernel writes a flag; each kernel no-ops
// unless flag==PID. Intermediates are always bf16.
// Workspace (64MB + flag word):
//   qkv: [0,48)   (dead after attn)
//   x2 : [0,16)   (after qkv dead; in-place updated by FF partial)
//   h2 : [16,32)
//   a  : [32,64)  (FF activation chunk, 4096 cols, reused 2x)
//   h  : [48,64)  (dead after qkv gemm)  /  o: [48,64) (after h dead)
//   flag: at min(64MB, ws_size-4)
// ---------------------------------------------------------------------------

typedef __attribute__((ext_vector_type(8))) short bf16x8;
typedef __attribute__((ext_vector_type(4))) float f32x4;

__device__ __forceinline__ float b2f(unsigned short u) {
    return __uint_as_float(((unsigned int)u) << 16);
}
__device__ __forceinline__ unsigned short f2b(float f) {
    unsigned int i = __float_as_uint(f);
    i += 0x7fffu + ((i >> 16) & 1u);   // RNE
    return (unsigned short)(i >> 16);
}

// ---- typed I/O helpers: DT=1 bf16, DT=0 f32 -------------------------------
template<int DT> struct IO;
template<> struct IO<1> {
    static __device__ __forceinline__ void load8(const void* p, size_t i, float* o) {
        uint4 v = *(const uint4*)((const unsigned short*)p + i);
        const unsigned short* u = (const unsigned short*)&v;
#pragma unroll
        for (int e = 0; e < 8; e++) o[e] = b2f(u[e]);
    }
    static __device__ __forceinline__ float load1(const void* p, size_t i) {
        return b2f(((const unsigned short*)p)[i]);
    }
    static __device__ __forceinline__ void store1(void* p, size_t i, float v) {
        ((unsigned short*)p)[i] = f2b(v);
    }
};
template<> struct IO<0> {
    static __device__ __forceinline__ void load8(const void* p, size_t i, float* o) {
        float4 a = *(const float4*)((const float*)p + i);
        float4 b = *(const float4*)((const float*)p + i + 4);
        o[0]=a.x; o[1]=a.y; o[2]=a.z; o[3]=a.w;
        o[4]=b.x; o[5]=b.y; o[6]=b.z; o[7]=b.w;
    }
    static __device__ __forceinline__ float load1(const void* p, size_t i) {
        return ((const float*)p)[i];
    }
    static __device__ __forceinline__ void store1(void* p, size_t i, float v) {
        ((float*)p)[i] = v;
    }
};

// ---------------------------------------------------------------------------
// Detector: classify x's encoding. flag = 1 (bf16) / 0 (f32).
// ---------------------------------------------------------------------------
__global__ __launch_bounds__(256) void detect_kernel(
    const unsigned int* __restrict__ x, int* __restrict__ flag)
{
    const int t = threadIdx.x;
    int cnt = 0;
    for (int i = t; i < 2048; i += 256) {
        unsigned int e = (x[i] >> 7) & 0xFFu;
        cnt += (e >= 100u && e <= 140u) ? 1 : 0;
    }
#pragma unroll
    for (int off = 32; off; off >>= 1) cnt += __shfl_xor(cnt, off);
    __shared__ int red[4];
    if ((t & 63) == 0) red[t >> 6] = cnt;
    __syncthreads();
    if (t == 0) {
        int tot = red[0] + red[1] + red[2] + red[3];
        flag[0] = (2 * tot > 2048) ? 1 : 0;
    }
}

// ---------------------------------------------------------------------------
// RMSNorm row kernel. X dtype DTX, weight DTW, output always bf16.
// ---------------------------------------------------------------------------
template<int PID, int DTX, int DTW>
__global__ __launch_bounds__(256) void rmsnorm_kernel(
    const int* __restrict__ flag,
    const void* __restrict__ X,
    const void* __restrict__ Wn,
    unsigned short* __restrict__ Out)
{
    if (flag[0] != PID) return;
    const int row = blockIdx.x, t = threadIdx.x;
    float xf[8];
    IO<DTX>::load8(X, (size_t)row * 2048 + t * 8, xf);
    float ss = 0.f;
#pragma unroll
    for (int e = 0; e < 8; e++) ss += xf[e] * xf[e];
#pragma unroll
    for (int off = 32; off; off >>= 1) ss += __shfl_xor(ss, off);
    __shared__ float red[4];
    if ((t & 63) == 0) red[t >> 6] = ss;
    __syncthreads();
    float rr = rsqrtf((red[0] + red[1] + red[2] + red[3]) * (1.0f / 2048.0f) + 1e-6f);
    float wf[8];
    IO<DTW>::load8(Wn, (size_t)t * 8, wf);
    unsigned short ob[8];
#pragma unroll
    for (int e = 0; e < 8; e++) ob[e] = f2b(xf[e] * rr * wf[e]);
    *(uint4*)(Out + (size_t)row * 2048 + t * 8) = *(uint4*)ob;
}

// ---------------------------------------------------------------------------
// GEMM: C(4096,N) = A(4096,K)bf16 @ W(N,ldw)^T [+ Res].
// 64x64 tile, BK=32, 4 waves x (2x2) mfma_16x16x32_bf16.
// ---------------------------------------------------------------------------
#define GBM 64
#define GBK 32
#define GPAD 8

template<int PID, int DTW, int DTR, int DTC, int EPI>
__global__ __launch_bounds__(256) void gemm_bt(
    const int* __restrict__ flag,
    const unsigned short* __restrict__ A,
    const void* __restrict__ W, size_t woff, int ldw,
    const void* __restrict__ Res,
    void* __restrict__ C,
    int N, int K)
{
    if (flag[0] != PID) return;
    __shared__ unsigned short sA[GBM][GBK + GPAD];
    __shared__ unsigned short sB[GBM][GBK + GPAD];
    const int t = threadIdx.x;
    const int bm = blockIdx.y * GBM, bn = blockIdx.x * GBM;
    const int w = t >> 6, lane = t & 63, quad = lane >> 4, l16 = lane & 15;
    const int wm = (w & 1) * 32, wn = (w >> 1) * 32;
    const int lr = t >> 2;         // 0..63
    const int lc = (t & 3) * 8;    // 0,8,16,24

    f32x4 zero = {0.f, 0.f, 0.f, 0.f};
    f32x4 acc[2][2] = {{zero, zero}, {zero, zero}};

    const unsigned short* Ap = A + (size_t)(bm + lr) * K + lc;
    const size_t wbase = woff + (size_t)(bn + lr) * ldw + lc;

    for (int k0 = 0; k0 < K; k0 += GBK) {
        uint4 av = *(const uint4*)(Ap + k0);
        float wf[8];
        IO<DTW>::load8(W, wbase + k0, wf);
        unsigned short wb[8];
#pragma unroll
        for (int e = 0; e < 8; e++) wb[e] = f2b(wf[e]);
        *(uint4*)&sA[lr][lc] = av;
        *(uint4*)&sB[lr][lc] = *(uint4*)wb;
        __syncthreads();
        bf16x8 af0 = *(const bf16x8*)&sA[wm + l16][quad * 8];
        bf16x8 af1 = *(const bf16x8*)&sA[wm + 16 + l16][quad * 8];
        bf16x8 bf0 = *(const bf16x8*)&sB[wn + l16][quad * 8];
        bf16x8 bf1 = *(const bf16x8*)&sB[wn + 16 + l16][quad * 8];
        acc[0][0] = __builtin_amdgcn_mfma_f32_16x16x32_bf16(af0, bf0, acc[0][0], 0, 0, 0);
        acc[0][1] = __builtin_amdgcn_mfma_f32_16x16x32_bf16(af0, bf1, acc[0][1], 0, 0, 0);
        acc[1][0] = __builtin_amdgcn_mfma_f32_16x16x32_bf16(af1, bf0, acc[1][0], 0, 0, 0);
        acc[1][1] = __builtin_amdgcn_mfma_f32_16x16x32_bf16(af1, bf1, acc[1][1], 0, 0, 0);
        __syncthreads();
    }

#pragma unroll
    for (int mi = 0; mi < 2; mi++)
#pragma unroll
        for (int ni = 0; ni < 2; ni++)
#pragma unroll
            for (int r = 0; r < 4; r++) {
                int row = bm + wm + mi * 16 + quad * 4 + r;
                int col = bn + wn + ni * 16 + l16;
                size_t idx = (size_t)row * N + col;
                float v = acc[mi][ni][r];
                if (EPI == 1) v += IO<DTR>::load1(Res, idx);
                IO<DTC>::store1(C, idx, v);
            }
}

// ---------------------------------------------------------------------------
// Fused gate/up GEMM chunk + SiLU.
// ---------------------------------------------------------------------------
template<int PID, int DTW>
__global__ __launch_bounds__(256) void gemm_gateup_silu(
    const int* __restrict__ flag,
    const unsigned short* __restrict__ A,
    const void* __restrict__ Wg,
    const void* __restrict__ Wu,
    size_t woff,                 // element offset = chunk_row * 2048
    unsigned short* __restrict__ Out,
    int N, int K)
{
    if (flag[0] != PID) return;
    __shared__ unsigned short sA[GBM][GBK + GPAD];
    __shared__ unsigned short sG[GBM][GBK + GPAD];
    __shared__ unsigned short sU[GBM][GBK + GPAD];
    const int t = threadIdx.x;
    const int bm = blockIdx.y * GBM, bn = blockIdx.x * GBM;
    const int w = t >> 6, lane = t & 63, quad = lane >> 4, l16 = lane & 15;
    const int wm = (w & 1) * 32, wn = (w >> 1) * 32;
    const int lr = t >> 2;
    const int lc = (t & 3) * 8;

    f32x4 zero = {0.f, 0.f, 0.f, 0.f};
    f32x4 accg[2][2] = {{zero, zero}, {zero, zero}};
    f32x4 accu[2][2] = {{zero, zero}, {zero, zero}};

    const unsigned short* Ap = A + (size_t)(bm + lr) * K + lc;
    const size_t wbase = woff + (size_t)(bn + lr) * K + lc;

    for (int k0 = 0; k0 < K; k0 += GBK) {
        uint4 av = *(const uint4*)(Ap + k0);
        float gf[8], uf[8];
        IO<DTW>::load8(Wg, wbase + k0, gf);
        IO<DTW>::load8(Wu, wbase + k0, uf);
        unsigned short gb[8], ub[8];
#pragma unroll
        for (int e = 0; e < 8; e++) { gb[e] = f2b(gf[e]); ub[e] = f2b(uf[e]); }
        *(uint4*)&sA[lr][lc] = av;
        *(uint4*)&sG[lr][lc] = *(uint4*)gb;
        *(uint4*)&sU[lr][lc] = *(uint4*)ub;
        __syncthreads();
        bf16x8 af0 = *(const bf16x8*)&sA[wm + l16][quad * 8];
        bf16x8 af1 = *(const bf16x8*)&sA[wm + 16 + l16][quad * 8];
        bf16x8 gf0 = *(const bf16x8*)&sG[wn + l16][quad * 8];
        bf16x8 gf1 = *(const bf16x8*)&sG[wn + 16 + l16][quad * 8];
        bf16x8 uf0 = *(const bf16x8*)&sU[wn + l16][quad * 8];
        bf16x8 uf1 = *(const bf16x8*)&sU[wn + 16 + l16][quad * 8];
        accg[0][0] = __builtin_amdgcn_mfma_f32_16x16x32_bf16(af0, gf0, accg[0][0], 0, 0, 0);
        accg[0][1] = __builtin_amdgcn_mfma_f32_16x16x32_bf16(af0, gf1, accg[0][1], 0, 0, 0);
        accg[1][0] = __builtin_amdgcn_mfma_f32_16x16x32_bf16(af1, gf0, accg[1][0], 0, 0, 0);
        accg[1][1] = __builtin_amdgcn_mfma_f32_16x16x32_bf16(af1, gf1, accg[1][1], 0, 0, 0);
        accu[0][0] = __builtin_amdgcn_mfma_f32_16x16x32_bf16(af0, uf0, accu[0][0], 0, 0, 0);
        accu[0][1] = __builtin_amdgcn_mfma_f32_16x16x32_bf16(af0, uf1, accu[0][1], 0, 0, 0);
        accu[1][0] = __builtin_amdgcn_mfma_f32_16x16x32_bf16(af1, uf0, accu[1][0], 0, 0, 0);
        accu[1][1] = __builtin_amdgcn_mfma_f32_16x16x32_bf16(af1, uf1, accu[1][1], 0, 0, 0);
        __syncthreads();
    }

#pragma unroll
    for (int mi = 0; mi < 2; mi++)
#pragma unroll
        for (int ni = 0; ni < 2; ni++)
#pragma unroll
            for (int r = 0; r < 4; r++) {
                int row = bm + wm + mi * 16 + quad * 4 + r;
                int col = bn + wn + ni * 16 + l16;
                float g = accg[mi][ni][r];
                float s = g / (1.f + __expf(-g));
                Out[(size_t)row * N + col] = f2b(s * accu[mi][ni][r]);
            }
}

// ---------------------------------------------------------------------------
// Flash-style MFMA attention. B=2, H=16, L=2048, HD=128.
// Grid 512: blockIdx = bh*16 + j; block processes q-tiles {j, 31-j} (64 rows
// each) -> 33 kv-tiles per block, perfectly balanced causal triangle.
// 4 waves x 64 lanes; wave w owns q rows [qt*64 + w*16, +16).
// Per kv-tile (KVBLK=64):
//   stage K XOR-swizzled [64][128],
//   stage V transposed Vt[d][kv]: stride 72, kv rotated IN-ROW by XOR with
//   (d & 56)  -> injective (offset stays in [0,64)), keeps 8-elem contiguity,
//   uniform bank spread for both transpose writes and b128 B-frag reads.
//   (Previous additive rotation overflowed the row at d=63->64 and aliased
//    48 slots of V[63][*] with V[64][*] -> absmax 0.51 failure.)
//   S = Q K^T via 16 mfma_16x16x32_bf16 / wave (scale applied to f32 S),
//   online softmax in-reg, P (bf16) -> per-wave LDS, O += P V via 16 mfma.
// LDS: 16384 (K) + 18560 (Vt) + 9216 (P) = 44160 B -> 3 blocks/CU.
// ---------------------------------------------------------------------------
__device__ __forceinline__ int vt_idx(int d, int kv) {
    return d * 72 + (kv ^ (d & 56));
}

template<int PID>
__global__ __launch_bounds__(256) void attn_kernel(
    const int* __restrict__ flag,
    const unsigned short* __restrict__ QKV,
    unsigned short* __restrict__ O)
{
    if (flag[0] != PID) return;
    __shared__ unsigned short sK[64 * 128];
    __shared__ unsigned short sVt[9280];
    __shared__ unsigned short sP[4][16 * 72];

    const int t = threadIdx.x;
    const int bh = blockIdx.x >> 4;      // 0..31
    const int jj = blockIdx.x & 15;      // 0..15
    const int b = bh >> 4, hh = bh & 15;
    const int w = t >> 6, lane = t & 63, quad = lane >> 4, l16 = lane & 15;

    const unsigned short* Qb = QKV + (size_t)(b * 2048) * 6144 + hh * 128;
    const unsigned short* Kb = Qb + 2048;
    const unsigned short* Vb = Qb + 4096;

    const int str = t >> 4;          // staging row (0..15), +16 per pass
    const int stc = (t & 15) * 8;    // staging col (0..120)

#pragma unroll
    for (int half = 0; half < 2; half++) {
        const int qt = half ? (31 - jj) : jj;
        const int qbase = qt * 64;

        // Q fragments (raw bf16). Lane holds Q[row=l16][k=ks*32+quad*8..+8]
        bf16x8 qf[4];
        {
            const unsigned short* qp = Qb + (size_t)(qbase + w * 16 + l16) * 6144;
#pragma unroll
            for (int ks = 0; ks < 4; ks++)
                qf[ks] = *(const bf16x8*)(qp + ks * 32 + quad * 8);
        }

        float m[4], l[4];
#pragma unroll
        for (int r = 0; r < 4; r++) { m[r] = -1e30f; l[r] = 0.f; }
        f32x4 accO[8];
#pragma unroll
        for (int d0 = 0; d0 < 8; d0++) {
            f32x4 z = {0.f, 0.f, 0.f, 0.f};
            accO[d0] = z;
        }

        for (int tk = 0; tk <= qt; tk++) {
            const int kv0 = tk * 64;
            __syncthreads();   // prior tile's LDS reads done before overwrite
            // ---- stage K (XOR swizzle) + V transposed (in-row XOR rot) ----
#pragma unroll
            for (int pass = 0; pass < 4; pass++) {
                const int rr = str + pass * 16;
                uint4 kv4 = *(const uint4*)(Kb + (size_t)(kv0 + rr) * 6144 + stc);
                *(uint4*)&sK[(rr * 128 + stc) ^ ((rr & 7) << 3)] = kv4;
                uint4 vv4 = *(const uint4*)(Vb + (size_t)(kv0 + rr) * 6144 + stc);
                const unsigned short* vu = (const unsigned short*)&vv4;
#pragma unroll
                for (int e = 0; e < 8; e++)
                    sVt[vt_idx(stc + e, rr)] = vu[e];
            }
            __syncthreads();

            // ---- S = Q K^T ----
            const bool diag = (tk == qt);
            f32x4 s[4];
#pragma unroll
            for (int nf = 0; nf < 4; nf++) {
                f32x4 z = {0.f, 0.f, 0.f, 0.f};
                s[nf] = z;
                if (!(diag && nf > w)) {     // fragment fully masked -> skip mfma
#pragma unroll
                    for (int ks = 0; ks < 4; ks++) {
                        const int row = nf * 16 + l16;
                        bf16x8 kf = *(const bf16x8*)
                            &sK[(row * 128 + ks * 32 + quad * 8) ^ ((row & 7) << 3)];
                        s[nf] = __builtin_amdgcn_mfma_f32_16x16x32_bf16(qf[ks], kf, s[nf], 0, 0, 0);
                    }
                }
#pragma unroll
                for (int r = 0; r < 4; r++) s[nf][r] *= 0.08838834764831845f;
            }
            if (diag) {
#pragma unroll
                for (int nf = 0; nf < 4; nf++)
#pragma unroll
                    for (int r = 0; r < 4; r++)
                        if (nf * 16 + l16 > w * 16 + quad * 4 + r) s[nf][r] = -1e30f;
            }

            // ---- online softmax (rows owned by quads; reduce over l16) ----
            float alpha[4], rs[4];
#pragma unroll
            for (int r = 0; r < 4; r++) {
                float v = fmaxf(fmaxf(s[0][r], s[1][r]), fmaxf(s[2][r], s[3][r]));
                v = fmaxf(v, __shfl_xor(v, 1));
                v = fmaxf(v, __shfl_xor(v, 2));
                v = fmaxf(v, __shfl_xor(v, 4));
                v = fmaxf(v, __shfl_xor(v, 8));
                float mn = fmaxf(m[r], v);
                alpha[r] = __expf(m[r] - mn);
                m[r] = mn;
                rs[r] = 0.f;
            }
#pragma unroll
            for (int nf = 0; nf < 4; nf++)
#pragma unroll
                for (int r = 0; r < 4; r++) {
                    float p = __expf(s[nf][r] - m[r]);
                    rs[r] += p;
                    sP[w][(quad * 4 + r) * 72 + nf * 16 + l16] = f2b(p);
                }
#pragma unroll
            for (int r = 0; r < 4; r++) {
                float sum = rs[r];
                sum += __shfl_xor(sum, 1);
                sum += __shfl_xor(sum, 2);
                sum += __shfl_xor(sum, 4);
                sum += __shfl_xor(sum, 8);
                l[r] = l[r] * alpha[r] + sum;
            }
#pragma unroll
            for (int d0 = 0; d0 < 8; d0++)
#pragma unroll
                for (int r = 0; r < 4; r++) accO[d0][r] *= alpha[r];

            // ---- O += P V  (A from own sP, B from sVt; same-wave LDS dep) ----
#pragma unroll
            for (int ks = 0; ks < 2; ks++) {
                bf16x8 pa = *(const bf16x8*)&sP[w][l16 * 72 + ks * 32 + quad * 8];
#pragma unroll
                for (int d0 = 0; d0 < 8; d0++) {
                    bf16x8 vb = *(const bf16x8*)
                        &sVt[vt_idx(d0 * 16 + l16, ks * 32 + quad * 8)];
                    accO[d0] = __builtin_amdgcn_mfma_f32_16x16x32_bf16(pa, vb, accO[d0], 0, 0, 0);
                }
            }
        }

        // ---- epilogue ----
        float linv[4];
#pragma unroll
        for (int r = 0; r < 4; r++) linv[r] = 1.0f / l[r];
        unsigned short* Op = O + (size_t)(b * 2048 + qbase + w * 16) * 2048 + hh * 128;
#pragma unroll
        for (int d0 = 0; d0 < 8; d0++)
#pragma unroll
            for (int r = 0; r < 4; r++)
                Op[(size_t)(quad * 4 + r) * 2048 + d0 * 16 + l16] =
                    f2b(accO[d0][r] * linv[r]);
    }
}

// ---------------------------------------------------------------------------
template<int DT>
static void run_pipeline(const void* x, const void* n1w, const void* qkvw,
                         const void* outw, const void* n2w, const void* gatew,
                         const void* upw, const void* downw,
                         void* outp, char* ws, const int* flag, hipStream_t stream)
{
    const size_t MB = 1024 * 1024;
    unsigned short* qkv = (unsigned short*)(ws);            // [0,48)
    unsigned short* x2  = (unsigned short*)(ws);            // [0,16) after qkv dead
    unsigned short* h2  = (unsigned short*)(ws + 16 * MB);  // [16,32)
    unsigned short* a   = (unsigned short*)(ws + 32 * MB);  // [32,64)
    unsigned short* h   = (unsigned short*)(ws + 48 * MB);  // [48,64)
    unsigned short* o   = (unsigned short*)(ws + 48 * MB);  // [48,64) after h dead

    // 1) h = rmsnorm(x, w1)
    rmsnorm_kernel<DT, DT, DT><<<4096, 256, 0, stream>>>(flag, x, n1w, h);
    // 2) qkv = h @ qkv_w^T  (N=6144, K=2048)
    gemm_bt<DT, DT, 1, 1, 0><<<dim3(96, 64), 256, 0, stream>>>(
        flag, h, qkvw, 0, 2048, nullptr, qkv, 6144, 2048);
    // 3) attention -> o   (flash MFMA, 512 balanced blocks)
    attn_kernel<DT><<<512, 256, 0, stream>>>(flag, qkv, o);
    // 4) x2 = x + o @ out_w^T  (N=2048, K=2048)   [qkv dead]
    gemm_bt<DT, DT, DT, 1, 1><<<dim3(32, 64), 256, 0, stream>>>(
        flag, o, outw, 0, 2048, x, x2, 2048, 2048);
    // 5) h2 = rmsnorm(x2, w2)
    rmsnorm_kernel<DT, 1, DT><<<4096, 256, 0, stream>>>(flag, x2, n2w, h2);
    // 6-9) FF in two chunks of 4096 FF-cols; x2 updated in place with partial.
    gemm_gateup_silu<DT, DT><<<dim3(64, 64), 256, 0, stream>>>(
        flag, h2, gatew, upw, (size_t)0, a, 4096, 2048);
    gemm_bt<DT, DT, 1, 1, 1><<<dim3(32, 64), 256, 0, stream>>>(
        flag, a, downw, 0, 8192, x2, x2, 2048, 4096);
    gemm_gateup_silu<DT, DT><<<dim3(64, 64), 256, 0, stream>>>(
        flag, h2, gatew, upw, (size_t)4096 * 2048, a, 4096, 2048);
    gemm_bt<DT, DT, 1, DT, 1><<<dim3(32, 64), 256, 0, stream>>>(
        flag, a, downw, 4096, 8192, x2, outp, 2048, 4096);
}

extern "C" void kernel_launch(void* const* d_in, const int* in_sizes, int n_in,
                              void* d_out, int out_size, void* d_ws, size_t ws_size,
                              hipStream_t stream)
{
    const void* x      = d_in[0];
    // d_in[1] = causal mask: implemented analytically, unused
    const void* n1w    = d_in[2];
    const void* qkv_w  = d_in[3];
    const void* out_w  = d_in[4];
    const void* n2w    = d_in[5];
    const void* gate_w = d_in[6];
    const void* up_w   = d_in[7];
    const void* down_w = d_in[8];

    char* ws = (char*)d_ws;
    const size_t MB = 1024 * 1024;
    size_t flag_off = 64 * MB;
    if (ws_size < flag_off + 4) flag_off = (ws_size - 4) & ~(size_t)3;
    int* flag = (int*)(ws + flag_off);

    detect_kernel<<<1, 256, 0, stream>>>((const unsigned int*)x, flag);
    run_pipeline<0>(x, n1w, qkv_w, out_w, n2w, gate_w, up_w, down_w,
                    d_out, ws, flag, stream);
    run_pipeline<1>(x, n1w, qkv_w, out_w, n2w, gate_w, up_w, down_w,
                    d_out, ws, flag, stream);
}

// Round 3
// 1312.959 us; speedup vs baseline: 2.3613x; 1.3192x over previous
//
#include <hip/hip_runtime.h>

// ---------------------------------------------------------------------------
// TransformerBlock: B=2, L=2048, D=2048, H=16, HD=128, FF=8192.
// Dual-dtype (runtime-detected): pipelines instantiated for DT=0 (f32 I/O)
// and DT=1 (bf16 I/O); a detector kernel writes a flag; each kernel no-ops
// unless flag==PID. Intermediates are always bf16.
// Workspace (64MB + flag word):
//   qkv: [0,48)   (dead after attn)
//   x2 : [0,16)   (after qkv dead; in-place updated by FF partial)
//   h2 : [16,32)
//   a  : [32,64)  (FF activation chunk, 4096 cols, reused 2x)
//   h  : [48,64)  (dead after qkv gemm)  /  o: [48,64) (after h dead)
//   flag: at min(64MB, ws_size-4)
// ---------------------------------------------------------------------------

typedef __attribute__((ext_vector_type(8))) short bf16x8;
typedef __attribute__((ext_vector_type(4))) float f32x4;

__device__ __forceinline__ float b2f(unsigned short u) {
    return __uint_as_float(((unsigned int)u) << 16);
}
__device__ __forceinline__ unsigned short f2b(float f) {
    unsigned int i = __float_as_uint(f);
    i += 0x7fffu + ((i >> 16) & 1u);   // RNE
    return (unsigned short)(i >> 16);
}

// async global->LDS, 16 B per lane; LDS dest is wave-uniform base + lane*16.
__device__ __forceinline__ void gload_lds16(const unsigned short* g, unsigned short* l) {
    __builtin_amdgcn_global_load_lds(
        (const __attribute__((address_space(1))) unsigned int*)g,
        (__attribute__((address_space(3))) unsigned int*)l,
        16, 0, 0);
}

// ---- typed I/O helpers: DT=1 bf16, DT=0 f32 -------------------------------
template<int DT> struct IO;
template<> struct IO<1> {
    static __device__ __forceinline__ void load8(const void* p, size_t i, float* o) {
        uint4 v = *(const uint4*)((const unsigned short*)p + i);
        const unsigned short* u = (const unsigned short*)&v;
#pragma unroll
        for (int e = 0; e < 8; e++) o[e] = b2f(u[e]);
    }
    static __device__ __forceinline__ float load1(const void* p, size_t i) {
        return b2f(((const unsigned short*)p)[i]);
    }
    static __device__ __forceinline__ void store1(void* p, size_t i, float v) {
        ((unsigned short*)p)[i] = f2b(v);
    }
};
template<> struct IO<0> {
    static __device__ __forceinline__ void load8(const void* p, size_t i, float* o) {
        float4 a = *(const float4*)((const float*)p + i);
        float4 b = *(const float4*)((const float*)p + i + 4);
        o[0]=a.x; o[1]=a.y; o[2]=a.z; o[3]=a.w;
        o[4]=b.x; o[5]=b.y; o[6]=b.z; o[7]=b.w;
    }
    static __device__ __forceinline__ float load1(const void* p, size_t i) {
        return ((const float*)p)[i];
    }
    static __device__ __forceinline__ void store1(void* p, size_t i, float v) {
        ((float*)p)[i] = v;
    }
};

// ---------------------------------------------------------------------------
// Detector: classify x's encoding. flag = 1 (bf16) / 0 (f32).
// ---------------------------------------------------------------------------
__global__ __launch_bounds__(256) void detect_kernel(
    const unsigned int* __restrict__ x, int* __restrict__ flag)
{
    const int t = threadIdx.x;
    int cnt = 0;
    for (int i = t; i < 2048; i += 256) {
        unsigned int e = (x[i] >> 7) & 0xFFu;
        cnt += (e >= 100u && e <= 140u) ? 1 : 0;
    }
#pragma unroll
    for (int off = 32; off; off >>= 1) cnt += __shfl_xor(cnt, off);
    __shared__ int red[4];
    if ((t & 63) == 0) red[t >> 6] = cnt;
    __syncthreads();
    if (t == 0) {
        int tot = red[0] + red[1] + red[2] + red[3];
        flag[0] = (2 * tot > 2048) ? 1 : 0;
    }
}

// ---------------------------------------------------------------------------
// RMSNorm row kernel. X dtype DTX, weight DTW, output always bf16.
// ---------------------------------------------------------------------------
template<int PID, int DTX, int DTW>
__global__ __launch_bounds__(256) void rmsnorm_kernel(
    const int* __restrict__ flag,
    const void* __restrict__ X,
    const void* __restrict__ Wn,
    unsigned short* __restrict__ Out)
{
    if (flag[0] != PID) return;
    const int row = blockIdx.x, t = threadIdx.x;
    float xf[8];
    IO<DTX>::load8(X, (size_t)row * 2048 + t * 8, xf);
    float ss = 0.f;
#pragma unroll
    for (int e = 0; e < 8; e++) ss += xf[e] * xf[e];
#pragma unroll
    for (int off = 32; off; off >>= 1) ss += __shfl_xor(ss, off);
    __shared__ float red[4];
    if ((t & 63) == 0) red[t >> 6] = ss;
    __syncthreads();
    float rr = rsqrtf((red[0] + red[1] + red[2] + red[3]) * (1.0f / 2048.0f) + 1e-6f);
    float wf[8];
    IO<DTW>::load8(Wn, (size_t)t * 8, wf);
    unsigned short ob[8];
#pragma unroll
    for (int e = 0; e < 8; e++) ob[e] = f2b(xf[e] * rr * wf[e]);
    *(uint4*)(Out + (size_t)row * 2048 + t * 8) = *(uint4*)ob;
}

// ---------------------------------------------------------------------------
// GEMM v2: C(4096,N) = A(4096,K)bf16 @ W(N,ldw)^T [+ epilogue].
// 128x128 tile, BK=64, 4 waves x (4x4) mfma_16x16x32_bf16 (64x64 per wave).
// LDS: linear [128][64] per matrix, XOR-swizzled at 16B-granule level:
//   slot s of row r holds granule s ^ (r&7)  -> ds_read_b128 is 2-way (free).
// A staged via global_load_lds (dest linear, SOURCE granule pre-swizzled:
//   lane l covers row r0+(l>>3), slot l&7, source granule (l&7)^(l>>3)).
// W staged same way when bf16 (DTW=1); reg-converted + swizzled ds_write_b128
// when f32 (DTW=0).
// EPI: 0=store, 1=+Res store, 2=silu store, 3=*Res store.
// ---------------------------------------------------------------------------
#define BM 128
#define BN 128
#define BKK 64

template<int PID, int DTW, int DTR, int DTC, int EPI>
__global__ __launch_bounds__(256) void gemm_bt(
    const int* __restrict__ flag,
    const unsigned short* __restrict__ A,
    const void* __restrict__ W, size_t woff, int ldw,
    const void* __restrict__ Res,
    void* __restrict__ C,
    int N, int K)
{
    if (flag[0] != PID) return;
    __shared__ unsigned short sA[BM * BKK];
    __shared__ unsigned short sB[BN * BKK];
    const int t = threadIdx.x;
    const int bm = blockIdx.y * BM, bn = blockIdx.x * BN;
    const int w = t >> 6, lane = t & 63, quad = lane >> 4, l16 = lane & 15;
    const int wm = (w & 1) * 64, wn = (w >> 1) * 64;

    const int srow = lane >> 3;               // row within 8-row issue group
    const int sg   = (lane & 7) ^ srow;       // pre-swizzled source granule

    f32x4 acc[4][4];
#pragma unroll
    for (int mi = 0; mi < 4; mi++)
#pragma unroll
        for (int ni = 0; ni < 4; ni++) {
            f32x4 z = {0.f, 0.f, 0.f, 0.f};
            acc[mi][ni] = z;
        }

    for (int k0 = 0; k0 < K; k0 += BKK) {
        // ---- stage A (always bf16, async direct-to-LDS) ----
#pragma unroll
        for (int i = 0; i < 4; i++) {
            const int r0 = w * 32 + i * 8;
            gload_lds16(A + (size_t)(bm + r0 + srow) * K + k0 + sg * 8,
                        &sA[r0 * BKK]);
        }
        // ---- stage B/W ----
        if constexpr (DTW == 1) {
#pragma unroll
            for (int i = 0; i < 4; i++) {
                const int r0 = w * 32 + i * 8;
                gload_lds16((const unsigned short*)W + woff +
                                (size_t)(bn + r0 + srow) * ldw + k0 + sg * 8,
                            &sB[r0 * BKK]);
            }
        } else {
#pragma unroll
            for (int i = 0; i < 4; i++) {
                const int r0 = w * 32 + i * 8;
                const int r = r0 + srow;
                const float* gp = (const float*)W + woff +
                                  (size_t)(bn + r) * ldw + k0 + (lane & 7) * 8;
                float4 f0 = *(const float4*)gp;
                float4 f1 = *(const float4*)(gp + 4);
                alignas(16) unsigned short wb[8] = {
                    f2b(f0.x), f2b(f0.y), f2b(f0.z), f2b(f0.w),
                    f2b(f1.x), f2b(f1.y), f2b(f1.z), f2b(f1.w)};
                *(uint4*)&sB[r * BKK + (((lane & 7) ^ (r & 7)) * 8)] = *(uint4*)wb;
            }
        }
        __syncthreads();   // drains vmcnt(0): LDS tiles complete

        // ---- compute: 2 k-subtiles x 16 mfma ----
#pragma unroll
        for (int ks = 0; ks < 2; ks++) {
            bf16x8 af[4], bfr[4];
#pragma unroll
            for (int mi = 0; mi < 4; mi++) {
                const int r = wm + mi * 16 + l16;
                af[mi] = *(const bf16x8*)
                    &sA[r * BKK + (((ks * 4 + quad) ^ (r & 7)) * 8)];
            }
#pragma unroll
            for (int ni = 0; ni < 4; ni++) {
                const int r = wn + ni * 16 + l16;
                bfr[ni] = *(const bf16x8*)
                    &sB[r * BKK + (((ks * 4 + quad) ^ (r & 7)) * 8)];
            }
#pragma unroll
            for (int mi = 0; mi < 4; mi++)
#pragma unroll
                for (int ni = 0; ni < 4; ni++)
                    acc[mi][ni] = __builtin_amdgcn_mfma_f32_16x16x32_bf16(
                        af[mi], bfr[ni], acc[mi][ni], 0, 0, 0);
        }
        __syncthreads();
    }

#pragma unroll
    for (int mi = 0; mi < 4; mi++)
#pragma unroll
        for (int ni = 0; ni < 4; ni++)
#pragma unroll
            for (int r = 0; r < 4; r++) {
                const int row = bm + wm + mi * 16 + quad * 4 + r;
                const int col = bn + wn + ni * 16 + l16;
                const size_t idx = (size_t)row * N + col;
                float v = acc[mi][ni][r];
                if constexpr (EPI == 1) v += IO<DTR>::load1(Res, idx);
                if constexpr (EPI == 2) v = v / (1.f + __expf(-v));
                if constexpr (EPI == 3) v *= IO<DTR>::load1(Res, idx);
                IO<DTC>::store1(C, idx, v);
            }
}

// ---------------------------------------------------------------------------
// Flash-style MFMA attention (unchanged from passing round-2 version).
// ---------------------------------------------------------------------------
__device__ __forceinline__ int vt_idx(int d, int kv) {
    return d * 72 + (kv ^ (d & 56));
}

template<int PID>
__global__ __launch_bounds__(256) void attn_kernel(
    const int* __restrict__ flag,
    const unsigned short* __restrict__ QKV,
    unsigned short* __restrict__ O)
{
    if (flag[0] != PID) return;
    __shared__ unsigned short sK[64 * 128];
    __shared__ unsigned short sVt[9280];
    __shared__ unsigned short sP[4][16 * 72];

    const int t = threadIdx.x;
    const int bh = blockIdx.x >> 4;      // 0..31
    const int jj = blockIdx.x & 15;      // 0..15
    const int b = bh >> 4, hh = bh & 15;
    const int w = t >> 6, lane = t & 63, quad = lane >> 4, l16 = lane & 15;

    const unsigned short* Qb = QKV + (size_t)(b * 2048) * 6144 + hh * 128;
    const unsigned short* Kb = Qb + 2048;
    const unsigned short* Vb = Qb + 4096;

    const int str = t >> 4;          // staging row (0..15), +16 per pass
    const int stc = (t & 15) * 8;    // staging col (0..120)

#pragma unroll
    for (int half = 0; half < 2; half++) {
        const int qt = half ? (31 - jj) : jj;
        const int qbase = qt * 64;

        bf16x8 qf[4];
        {
            const unsigned short* qp = Qb + (size_t)(qbase + w * 16 + l16) * 6144;
#pragma unroll
            for (int ks = 0; ks < 4; ks++)
                qf[ks] = *(const bf16x8*)(qp + ks * 32 + quad * 8);
        }

        float m[4], l[4];
#pragma unroll
        for (int r = 0; r < 4; r++) { m[r] = -1e30f; l[r] = 0.f; }
        f32x4 accO[8];
#pragma unroll
        for (int d0 = 0; d0 < 8; d0++) {
            f32x4 z = {0.f, 0.f, 0.f, 0.f};
            accO[d0] = z;
        }

        for (int tk = 0; tk <= qt; tk++) {
            const int kv0 = tk * 64;
            __syncthreads();
#pragma unroll
            for (int pass = 0; pass < 4; pass++) {
                const int rr = str + pass * 16;
                uint4 kv4 = *(const uint4*)(Kb + (size_t)(kv0 + rr) * 6144 + stc);
                *(uint4*)&sK[(rr * 128 + stc) ^ ((rr & 7) << 3)] = kv4;
                uint4 vv4 = *(const uint4*)(Vb + (size_t)(kv0 + rr) * 6144 + stc);
                const unsigned short* vu = (const unsigned short*)&vv4;
#pragma unroll
                for (int e = 0; e < 8; e++)
                    sVt[vt_idx(stc + e, rr)] = vu[e];
            }
            __syncthreads();

            const bool diag = (tk == qt);
            f32x4 s[4];
#pragma unroll
            for (int nf = 0; nf < 4; nf++) {
                f32x4 z = {0.f, 0.f, 0.f, 0.f};
                s[nf] = z;
                if (!(diag && nf > w)) {
#pragma unroll
                    for (int ks = 0; ks < 4; ks++) {
                        const int row = nf * 16 + l16;
                        bf16x8 kf = *(const bf16x8*)
                            &sK[(row * 128 + ks * 32 + quad * 8) ^ ((row & 7) << 3)];
                        s[nf] = __builtin_amdgcn_mfma_f32_16x16x32_bf16(qf[ks], kf, s[nf], 0, 0, 0);
                    }
                }
#pragma unroll
                for (int r = 0; r < 4; r++) s[nf][r] *= 0.08838834764831845f;
            }
            if (diag) {
#pragma unroll
                for (int nf = 0; nf < 4; nf++)
#pragma unroll
                    for (int r = 0; r < 4; r++)
                        if (nf * 16 + l16 > w * 16 + quad * 4 + r) s[nf][r] = -1e30f;
            }

            float alpha[4], rs[4];
#pragma unroll
            for (int r = 0; r < 4; r++) {
                float v = fmaxf(fmaxf(s[0][r], s[1][r]), fmaxf(s[2][r], s[3][r]));
                v = fmaxf(v, __shfl_xor(v, 1));
                v = fmaxf(v, __shfl_xor(v, 2));
                v = fmaxf(v, __shfl_xor(v, 4));
                v = fmaxf(v, __shfl_xor(v, 8));
                float mn = fmaxf(m[r], v);
                alpha[r] = __expf(m[r] - mn);
                m[r] = mn;
                rs[r] = 0.f;
            }
#pragma unroll
            for (int nf = 0; nf < 4; nf++)
#pragma unroll
                for (int r = 0; r < 4; r++) {
                    float p = __expf(s[nf][r] - m[r]);
                    rs[r] += p;
                    sP[w][(quad * 4 + r) * 72 + nf * 16 + l16] = f2b(p);
                }
#pragma unroll
            for (int r = 0; r < 4; r++) {
                float sum = rs[r];
                sum += __shfl_xor(sum, 1);
                sum += __shfl_xor(sum, 2);
                sum += __shfl_xor(sum, 4);
                sum += __shfl_xor(sum, 8);
                l[r] = l[r] * alpha[r] + sum;
            }
#pragma unroll
            for (int d0 = 0; d0 < 8; d0++)
#pragma unroll
                for (int r = 0; r < 4; r++) accO[d0][r] *= alpha[r];

#pragma unroll
            for (int ks = 0; ks < 2; ks++) {
                bf16x8 pa = *(const bf16x8*)&sP[w][l16 * 72 + ks * 32 + quad * 8];
#pragma unroll
                for (int d0 = 0; d0 < 8; d0++) {
                    bf16x8 vb = *(const bf16x8*)
                        &sVt[vt_idx(d0 * 16 + l16, ks * 32 + quad * 8)];
                    accO[d0] = __builtin_amdgcn_mfma_f32_16x16x32_bf16(pa, vb, accO[d0], 0, 0, 0);
                }
            }
        }

        float linv[4];
#pragma unroll
        for (int r = 0; r < 4; r++) linv[r] = 1.0f / l[r];
        unsigned short* Op = O + (size_t)(b * 2048 + qbase + w * 16) * 2048 + hh * 128;
#pragma unroll
        for (int d0 = 0; d0 < 8; d0++)
#pragma unroll
            for (int r = 0; r < 4; r++)
                Op[(size_t)(quad * 4 + r) * 2048 + d0 * 16 + l16] =
                    f2b(accO[d0][r] * linv[r]);
    }
}

// ---------------------------------------------------------------------------
template<int DT>
static void run_pipeline(const void* x, const void* n1w, const void* qkvw,
                         const void* outw, const void* n2w, const void* gatew,
                         const void* upw, const void* downw,
                         void* outp, char* ws, const int* flag, hipStream_t stream)
{
    const size_t MB = 1024 * 1024;
    unsigned short* qkv = (unsigned short*)(ws);            // [0,48)
    unsigned short* x2  = (unsigned short*)(ws);            // [0,16) after qkv dead
    unsigned short* h2  = (unsigned short*)(ws + 16 * MB);  // [16,32)
    unsigned short* a   = (unsigned short*)(ws + 32 * MB);  // [32,64)
    unsigned short* h   = (unsigned short*)(ws + 48 * MB);  // [48,64)
    unsigned short* o   = (unsigned short*)(ws + 48 * MB);  // [48,64) after h dead

    // 1) h = rmsnorm(x, w1)
    rmsnorm_kernel<DT, DT, DT><<<4096, 256, 0, stream>>>(flag, x, n1w, h);
    // 2) qkv = h @ qkv_w^T  (N=6144, K=2048)
    gemm_bt<DT, DT, 1, 1, 0><<<dim3(48, 32), 256, 0, stream>>>(
        flag, h, qkvw, 0, 2048, nullptr, qkv, 6144, 2048);
    // 3) attention -> o
    attn_kernel<DT><<<512, 256, 0, stream>>>(flag, qkv, o);
    // 4) x2 = x + o @ out_w^T  (N=2048, K=2048)   [qkv dead]
    gemm_bt<DT, DT, DT, 1, 1><<<dim3(16, 32), 256, 0, stream>>>(
        flag, o, outw, 0, 2048, x, x2, 2048, 2048);
    // 5) h2 = rmsnorm(x2, w2)
    rmsnorm_kernel<DT, 1, DT><<<4096, 256, 0, stream>>>(flag, x2, n2w, h2);
    // 6-11) FF in two chunks of 4096 FF-cols:
    //   a = silu(h2 @ gate^T); a *= h2 @ up^T; x2/out += a @ down^T
    // chunk 0
    gemm_bt<DT, DT, 1, 1, 2><<<dim3(32, 32), 256, 0, stream>>>(
        flag, h2, gatew, 0, 2048, nullptr, a, 4096, 2048);
    gemm_bt<DT, DT, 1, 1, 3><<<dim3(32, 32), 256, 0, stream>>>(
        flag, h2, upw, 0, 2048, a, a, 4096, 2048);
    gemm_bt<DT, DT, 1, 1, 1><<<dim3(16, 32), 256, 0, stream>>>(
        flag, a, downw, 0, 8192, x2, x2, 2048, 4096);
    // chunk 1
    gemm_bt<DT, DT, 1, 1, 2><<<dim3(32, 32), 256, 0, stream>>>(
        flag, h2, gatew, (size_t)4096 * 2048, 2048, nullptr, a, 4096, 2048);
    gemm_bt<DT, DT, 1, 1, 3><<<dim3(32, 32), 256, 0, stream>>>(
        flag, h2, upw, (size_t)4096 * 2048, 2048, a, a, 4096, 2048);
    gemm_bt<DT, DT, 1, DT, 1><<<dim3(16, 32), 256, 0, stream>>>(
        flag, a, downw, 4096, 8192, x2, outp, 2048, 4096);
}

extern "C" void kernel_launch(void* const* d_in, const int* in_sizes, int n_in,
                              void* d_out, int out_size, void* d_ws, size_t ws_size,
                              hipStream_t stream)
{
    const void* x      = d_in[0];
    // d_in[1] = causal mask: implemented analytically, unused
    const void* n1w    = d_in[2];
    const void* qkv_w  = d_in[3];
    const void* out_w  = d_in[4];
    const void* n2w    = d_in[5];
    const void* gate_w = d_in[6];
    const void* up_w   = d_in[7];
    const void* down_w = d_in[8];

    char* ws = (char*)d_ws;
    const size_t MB = 1024 * 1024;
    size_t flag_off = 64 * MB;
    if (ws_size < flag_off + 4) flag_off = (ws_size - 4) & ~(size_t)3;
    int* flag = (int*)(ws + flag_off);

    detect_kernel<<<1, 256, 0, stream>>>((const unsigned int*)x, flag);
    run_pipeline<0>(x, n1w, qkv_w, out_w, n2w, gate_w, up_w, down_w,
                    d_out, ws, flag, stream);
    run_pipeline<1>(x, n1w, qkv_w, out_w, n2w, gate_w, up_w, down_w,
                    d_out, ws, flag, stream);
}

// Round 4
// 1290.296 us; speedup vs baseline: 2.4027x; 1.0176x over previous
//
#include <hip/hip_runtime.h>

// ---------------------------------------------------------------------------
// TransformerBlock: B=2, L=2048, D=2048, H=16, HD=128, FF=8192.
// Dual-dtype (runtime-detected): pipelines instantiated for DT=0 (f32 I/O)
// and DT=1 (bf16 I/O); a detector kernel writes a flag; each kernel no-ops
// unless flag==PID. Intermediates are always bf16.
// Workspace (64MB + flag word):
//   qkv: [0,48)   (dead after attn)
//   x2 : [0,16)   (after qkv dead; in-place updated by FF partial)
//   h2 : [16,32)
//   a  : [32,64)  (FF activation chunk, 4096 cols, reused 2x)
//   h  : [48,64)  (dead after qkv gemm)  /  o: [48,64) (after h dead)
//   flag: at min(64MB, ws_size-4)
// ---------------------------------------------------------------------------

typedef __attribute__((ext_vector_type(8))) short bf16x8;
typedef __attribute__((ext_vector_type(4))) float f32x4;

__device__ __forceinline__ float b2f(unsigned short u) {
    return __uint_as_float(((unsigned int)u) << 16);
}
__device__ __forceinline__ unsigned short f2b(float f) {
    unsigned int i = __float_as_uint(f);
    i += 0x7fffu + ((i >> 16) & 1u);   // RNE
    return (unsigned short)(i >> 16);
}
// packed f32x2 -> bf16x2 (RNE), single VALU op; no builtin on gfx950
__device__ __forceinline__ unsigned int cvt_pk_bf16(float lo, float hi) {
    unsigned int r;
    asm("v_cvt_pk_bf16_f32 %0, %1, %2" : "=v"(r) : "v"(lo), "v"(hi));
    return r;
}

// async global->LDS, 16 B per lane; LDS dest is wave-uniform base + lane*16.
__device__ __forceinline__ void gload_lds16(const unsigned short* g, unsigned short* l) {
    __builtin_amdgcn_global_load_lds(
        (const __attribute__((address_space(1))) unsigned int*)g,
        (__attribute__((address_space(3))) unsigned int*)l,
        16, 0, 0);
}

// ---- typed I/O helpers: DT=1 bf16, DT=0 f32 -------------------------------
template<int DT> struct IO;
template<> struct IO<1> {
    static __device__ __forceinline__ void load8(const void* p, size_t i, float* o) {
        uint4 v = *(const uint4*)((const unsigned short*)p + i);
        const unsigned short* u = (const unsigned short*)&v;
#pragma unroll
        for (int e = 0; e < 8; e++) o[e] = b2f(u[e]);
    }
    static __device__ __forceinline__ float load1(const void* p, size_t i) {
        return b2f(((const unsigned short*)p)[i]);
    }
    static __device__ __forceinline__ void store1(void* p, size_t i, float v) {
        ((unsigned short*)p)[i] = f2b(v);
    }
};
template<> struct IO<0> {
    static __device__ __forceinline__ void load8(const void* p, size_t i, float* o) {
        float4 a = *(const float4*)((const float*)p + i);
        float4 b = *(const float4*)((const float*)p + i + 4);
        o[0]=a.x; o[1]=a.y; o[2]=a.z; o[3]=a.w;
        o[4]=b.x; o[5]=b.y; o[6]=b.z; o[7]=b.w;
    }
    static __device__ __forceinline__ float load1(const void* p, size_t i) {
        return ((const float*)p)[i];
    }
    static __device__ __forceinline__ void store1(void* p, size_t i, float v) {
        ((float*)p)[i] = v;
    }
};

// ---------------------------------------------------------------------------
// Detector: classify x's encoding. flag = 1 (bf16) / 0 (f32).
// ---------------------------------------------------------------------------
__global__ __launch_bounds__(256) void detect_kernel(
    const unsigned int* __restrict__ x, int* __restrict__ flag)
{
    const int t = threadIdx.x;
    int cnt = 0;
    for (int i = t; i < 2048; i += 256) {
        unsigned int e = (x[i] >> 7) & 0xFFu;
        cnt += (e >= 100u && e <= 140u) ? 1 : 0;
    }
#pragma unroll
    for (int off = 32; off; off >>= 1) cnt += __shfl_xor(cnt, off);
    __shared__ int red[4];
    if ((t & 63) == 0) red[t >> 6] = cnt;
    __syncthreads();
    if (t == 0) {
        int tot = red[0] + red[1] + red[2] + red[3];
        flag[0] = (2 * tot > 2048) ? 1 : 0;
    }
}

// ---------------------------------------------------------------------------
// RMSNorm row kernel. X dtype DTX, weight DTW, output always bf16.
// ---------------------------------------------------------------------------
template<int PID, int DTX, int DTW>
__global__ __launch_bounds__(256) void rmsnorm_kernel(
    const int* __restrict__ flag,
    const void* __restrict__ X,
    const void* __restrict__ Wn,
    unsigned short* __restrict__ Out)
{
    if (flag[0] != PID) return;
    const int row = blockIdx.x, t = threadIdx.x;
    float xf[8];
    IO<DTX>::load8(X, (size_t)row * 2048 + t * 8, xf);
    float ss = 0.f;
#pragma unroll
    for (int e = 0; e < 8; e++) ss += xf[e] * xf[e];
#pragma unroll
    for (int off = 32; off; off >>= 1) ss += __shfl_xor(ss, off);
    __shared__ float red[4];
    if ((t & 63) == 0) red[t >> 6] = ss;
    __syncthreads();
    float rr = rsqrtf((red[0] + red[1] + red[2] + red[3]) * (1.0f / 2048.0f) + 1e-6f);
    float wf[8];
    IO<DTW>::load8(Wn, (size_t)t * 8, wf);
    float y[8];
#pragma unroll
    for (int e = 0; e < 8; e++) y[e] = xf[e] * rr * wf[e];
    uint4 ov;
    ov.x = cvt_pk_bf16(y[0], y[1]);
    ov.y = cvt_pk_bf16(y[2], y[3]);
    ov.z = cvt_pk_bf16(y[4], y[5]);
    ov.w = cvt_pk_bf16(y[6], y[7]);
    *(uint4*)(Out + (size_t)row * 2048 + t * 8) = ov;
}

// ---------------------------------------------------------------------------
// GEMM v2: C(4096,N) = A(4096,K)bf16 @ W(N,ldw)^T [+ epilogue].
// 128x128 tile, BK=64, 4 waves x (4x4) mfma_16x16x32_bf16 (64x64 per wave).
// Grid: x = M-tiles (consecutive blocks share the B tile -> L2 reuse),
//       y = N-tiles.
// LDS: linear [128][64] per matrix, XOR-swizzled at 16B-granule level:
//   slot s of row r holds granule s ^ (r&7)  -> ds_read_b128 is 2-way (free).
// A staged via global_load_lds (dest linear, SOURCE granule pre-swizzled).
// W staged same way when bf16 (DTW=1); reg-converted via v_cvt_pk_bf16_f32
// (4 ops per 8 elems) + swizzled ds_write_b128 when f32 (DTW=0).
// EPI: 0=store, 1=+Res store, 2=silu store, 3=*Res store.
// ---------------------------------------------------------------------------
#define BM 128
#define BN 128
#define BKK 64

template<int PID, int DTW, int DTR, int DTC, int EPI>
__global__ __launch_bounds__(256) void gemm_bt(
    const int* __restrict__ flag,
    const unsigned short* __restrict__ A,
    const void* __restrict__ W, size_t woff, int ldw,
    const void* __restrict__ Res,
    void* __restrict__ C,
    int N, int K)
{
    if (flag[0] != PID) return;
    __shared__ unsigned short sA[BM * BKK];
    __shared__ unsigned short sB[BN * BKK];
    const int t = threadIdx.x;
    const int bm = blockIdx.x * BM, bn = blockIdx.y * BN;
    const int w = t >> 6, lane = t & 63, quad = lane >> 4, l16 = lane & 15;
    const int wm = (w & 1) * 64, wn = (w >> 1) * 64;

    const int srow = lane >> 3;               // row within 8-row issue group
    const int sg   = (lane & 7) ^ srow;       // pre-swizzled source granule

    f32x4 acc[4][4];
#pragma unroll
    for (int mi = 0; mi < 4; mi++)
#pragma unroll
        for (int ni = 0; ni < 4; ni++) {
            f32x4 z = {0.f, 0.f, 0.f, 0.f};
            acc[mi][ni] = z;
        }

    for (int k0 = 0; k0 < K; k0 += BKK) {
        // ---- stage A (always bf16, async direct-to-LDS) ----
#pragma unroll
        for (int i = 0; i < 4; i++) {
            const int r0 = w * 32 + i * 8;
            gload_lds16(A + (size_t)(bm + r0 + srow) * K + k0 + sg * 8,
                        &sA[r0 * BKK]);
        }
        // ---- stage B/W ----
        if constexpr (DTW == 1) {
#pragma unroll
            for (int i = 0; i < 4; i++) {
                const int r0 = w * 32 + i * 8;
                gload_lds16((const unsigned short*)W + woff +
                                (size_t)(bn + r0 + srow) * ldw + k0 + sg * 8,
                            &sB[r0 * BKK]);
            }
        } else {
#pragma unroll
            for (int i = 0; i < 4; i++) {
                const int r0 = w * 32 + i * 8;
                const int r = r0 + srow;
                const float* gp = (const float*)W + woff +
                                  (size_t)(bn + r) * ldw + k0 + (lane & 7) * 8;
                float4 f0 = *(const float4*)gp;
                float4 f1 = *(const float4*)(gp + 4);
                uint4 wb;
                wb.x = cvt_pk_bf16(f0.x, f0.y);
                wb.y = cvt_pk_bf16(f0.z, f0.w);
                wb.z = cvt_pk_bf16(f1.x, f1.y);
                wb.w = cvt_pk_bf16(f1.z, f1.w);
                *(uint4*)&sB[r * BKK + (((lane & 7) ^ (r & 7)) * 8)] = wb;
            }
        }
        __syncthreads();   // drains vmcnt(0): LDS tiles complete

        // ---- compute: 2 k-subtiles x 16 mfma ----
#pragma unroll
        for (int ks = 0; ks < 2; ks++) {
            bf16x8 af[4], bfr[4];
#pragma unroll
            for (int mi = 0; mi < 4; mi++) {
                const int r = wm + mi * 16 + l16;
                af[mi] = *(const bf16x8*)
                    &sA[r * BKK + (((ks * 4 + quad) ^ (r & 7)) * 8)];
            }
#pragma unroll
            for (int ni = 0; ni < 4; ni++) {
                const int r = wn + ni * 16 + l16;
                bfr[ni] = *(const bf16x8*)
                    &sB[r * BKK + (((ks * 4 + quad) ^ (r & 7)) * 8)];
            }
#pragma unroll
            for (int mi = 0; mi < 4; mi++)
#pragma unroll
                for (int ni = 0; ni < 4; ni++)
                    acc[mi][ni] = __builtin_amdgcn_mfma_f32_16x16x32_bf16(
                        af[mi], bfr[ni], acc[mi][ni], 0, 0, 0);
        }
        __syncthreads();
    }

#pragma unroll
    for (int mi = 0; mi < 4; mi++)
#pragma unroll
        for (int ni = 0; ni < 4; ni++)
#pragma unroll
            for (int r = 0; r < 4; r++) {
                const int row = bm + wm + mi * 16 + quad * 4 + r;
                const int col = bn + wn + ni * 16 + l16;
                const size_t idx = (size_t)row * N + col;
                float v = acc[mi][ni][r];
                if constexpr (EPI == 1) v += IO<DTR>::load1(Res, idx);
                if constexpr (EPI == 2) v = v / (1.f + __expf(-v));
                if constexpr (EPI == 3) v *= IO<DTR>::load1(Res, idx);
                IO<DTC>::store1(C, idx, v);
            }
}

// ---------------------------------------------------------------------------
// Flash-style MFMA attention (unchanged from passing round-2 version).
// ---------------------------------------------------------------------------
__device__ __forceinline__ int vt_idx(int d, int kv) {
    return d * 72 + (kv ^ (d & 56));
}

template<int PID>
__global__ __launch_bounds__(256) void attn_kernel(
    const int* __restrict__ flag,
    const unsigned short* __restrict__ QKV,
    unsigned short* __restrict__ O)
{
    if (flag[0] != PID) return;
    __shared__ unsigned short sK[64 * 128];
    __shared__ unsigned short sVt[9280];
    __shared__ unsigned short sP[4][16 * 72];

    const int t = threadIdx.x;
    const int bh = blockIdx.x >> 4;      // 0..31
    const int jj = blockIdx.x & 15;      // 0..15
    const int b = bh >> 4, hh = bh & 15;
    const int w = t >> 6, lane = t & 63, quad = lane >> 4, l16 = lane & 15;

    const unsigned short* Qb = QKV + (size_t)(b * 2048) * 6144 + hh * 128;
    const unsigned short* Kb = Qb + 2048;
    const unsigned short* Vb = Qb + 4096;

    const int str = t >> 4;          // staging row (0..15), +16 per pass
    const int stc = (t & 15) * 8;    // staging col (0..120)

#pragma unroll
    for (int half = 0; half < 2; half++) {
        const int qt = half ? (31 - jj) : jj;
        const int qbase = qt * 64;

        bf16x8 qf[4];
        {
            const unsigned short* qp = Qb + (size_t)(qbase + w * 16 + l16) * 6144;
#pragma unroll
            for (int ks = 0; ks < 4; ks++)
                qf[ks] = *(const bf16x8*)(qp + ks * 32 + quad * 8);
        }

        float m[4], l[4];
#pragma unroll
        for (int r = 0; r < 4; r++) { m[r] = -1e30f; l[r] = 0.f; }
        f32x4 accO[8];
#pragma unroll
        for (int d0 = 0; d0 < 8; d0++) {
            f32x4 z = {0.f, 0.f, 0.f, 0.f};
            accO[d0] = z;
        }

        for (int tk = 0; tk <= qt; tk++) {
            const int kv0 = tk * 64;
            __syncthreads();
#pragma unroll
            for (int pass = 0; pass < 4; pass++) {
                const int rr = str + pass * 16;
                uint4 kv4 = *(const uint4*)(Kb + (size_t)(kv0 + rr) * 6144 + stc);
                *(uint4*)&sK[(rr * 128 + stc) ^ ((rr & 7) << 3)] = kv4;
                uint4 vv4 = *(const uint4*)(Vb + (size_t)(kv0 + rr) * 6144 + stc);
                const unsigned short* vu = (const unsigned short*)&vv4;
#pragma unroll
                for (int e = 0; e < 8; e++)
                    sVt[vt_idx(stc + e, rr)] = vu[e];
            }
            __syncthreads();

            const bool diag = (tk == qt);
            f32x4 s[4];
#pragma unroll
            for (int nf = 0; nf < 4; nf++) {
                f32x4 z = {0.f, 0.f, 0.f, 0.f};
                s[nf] = z;
                if (!(diag && nf > w)) {
#pragma unroll
                    for (int ks = 0; ks < 4; ks++) {
                        const int row = nf * 16 + l16;
                        bf16x8 kf = *(const bf16x8*)
                            &sK[(row * 128 + ks * 32 + quad * 8) ^ ((row & 7) << 3)];
                        s[nf] = __builtin_amdgcn_mfma_f32_16x16x32_bf16(qf[ks], kf, s[nf], 0, 0, 0);
                    }
                }
#pragma unroll
                for (int r = 0; r < 4; r++) s[nf][r] *= 0.08838834764831845f;
            }
            if (diag) {
#pragma unroll
                for (int nf = 0; nf < 4; nf++)
#pragma unroll
                    for (int r = 0; r < 4; r++)
                        if (nf * 16 + l16 > w * 16 + quad * 4 + r) s[nf][r] = -1e30f;
            }

            float alpha[4], rs[4];
#pragma unroll
            for (int r = 0; r < 4; r++) {
                float v = fmaxf(fmaxf(s[0][r], s[1][r]), fmaxf(s[2][r], s[3][r]));
                v = fmaxf(v, __shfl_xor(v, 1));
                v = fmaxf(v, __shfl_xor(v, 2));
                v = fmaxf(v, __shfl_xor(v, 4));
                v = fmaxf(v, __shfl_xor(v, 8));
                float mn = fmaxf(m[r], v);
                alpha[r] = __expf(m[r] - mn);
                m[r] = mn;
                rs[r] = 0.f;
            }
#pragma unroll
            for (int nf = 0; nf < 4; nf++)
#pragma unroll
                for (int r = 0; r < 4; r++) {
                    float p = __expf(s[nf][r] - m[r]);
                    rs[r] += p;
                    sP[w][(quad * 4 + r) * 72 + nf * 16 + l16] = f2b(p);
                }
#pragma unroll
            for (int r = 0; r < 4; r++) {
                float sum = rs[r];
                sum += __shfl_xor(sum, 1);
                sum += __shfl_xor(sum, 2);
                sum += __shfl_xor(sum, 4);
                sum += __shfl_xor(sum, 8);
                l[r] = l[r] * alpha[r] + sum;
            }
#pragma unroll
            for (int d0 = 0; d0 < 8; d0++)
#pragma unroll
                for (int r = 0; r < 4; r++) accO[d0][r] *= alpha[r];

#pragma unroll
            for (int ks = 0; ks < 2; ks++) {
                bf16x8 pa = *(const bf16x8*)&sP[w][l16 * 72 + ks * 32 + quad * 8];
#pragma unroll
                for (int d0 = 0; d0 < 8; d0++) {
                    bf16x8 vb = *(const bf16x8*)
                        &sVt[vt_idx(d0 * 16 + l16, ks * 32 + quad * 8)];
                    accO[d0] = __builtin_amdgcn_mfma_f32_16x16x32_bf16(pa, vb, accO[d0], 0, 0, 0);
                }
            }
        }

        float linv[4];
#pragma unroll
        for (int r = 0; r < 4; r++) linv[r] = 1.0f / l[r];
        unsigned short* Op = O + (size_t)(b * 2048 + qbase + w * 16) * 2048 + hh * 128;
#pragma unroll
        for (int d0 = 0; d0 < 8; d0++)
#pragma unroll
            for (int r = 0; r < 4; r++)
                Op[(size_t)(quad * 4 + r) * 2048 + d0 * 16 + l16] =
                    f2b(accO[d0][r] * linv[r]);
    }
}

// ---------------------------------------------------------------------------
template<int DT>
static void run_pipeline(const void* x, const void* n1w, const void* qkvw,
                         const void* outw, const void* n2w, const void* gatew,
                         const void* upw, const void* downw,
                         void* outp, char* ws, const int* flag, hipStream_t stream)
{
    const size_t MB = 1024 * 1024;
    unsigned short* qkv = (unsigned short*)(ws);            // [0,48)
    unsigned short* x2  = (unsigned short*)(ws);            // [0,16) after qkv dead
    unsigned short* h2  = (unsigned short*)(ws + 16 * MB);  // [16,32)
    unsigned short* a   = (unsigned short*)(ws + 32 * MB);  // [32,64)
    unsigned short* h   = (unsigned short*)(ws + 48 * MB);  // [48,64)
    unsigned short* o   = (unsigned short*)(ws + 48 * MB);  // [48,64) after h dead

    // 1) h = rmsnorm(x, w1)
    rmsnorm_kernel<DT, DT, DT><<<4096, 256, 0, stream>>>(flag, x, n1w, h);
    // 2) qkv = h @ qkv_w^T  (N=6144, K=2048)
    gemm_bt<DT, DT, 1, 1, 0><<<dim3(32, 48), 256, 0, stream>>>(
        flag, h, qkvw, 0, 2048, nullptr, qkv, 6144, 2048);
    // 3) attention -> o
    attn_kernel<DT><<<512, 256, 0, stream>>>(flag, qkv, o);
    // 4) x2 = x + o @ out_w^T  (N=2048, K=2048)   [qkv dead]
    gemm_bt<DT, DT, DT, 1, 1><<<dim3(32, 16), 256, 0, stream>>>(
        flag, o, outw, 0, 2048, x, x2, 2048, 2048);
    // 5) h2 = rmsnorm(x2, w2)
    rmsnorm_kernel<DT, 1, DT><<<4096, 256, 0, stream>>>(flag, x2, n2w, h2);
    // 6-11) FF in two chunks of 4096 FF-cols:
    //   a = silu(h2 @ gate^T); a *= h2 @ up^T; x2/out += a @ down^T
    // chunk 0
    gemm_bt<DT, DT, 1, 1, 2><<<dim3(32, 32), 256, 0, stream>>>(
        flag, h2, gatew, 0, 2048, nullptr, a, 4096, 2048);
    gemm_bt<DT, DT, 1, 1, 3><<<dim3(32, 32), 256, 0, stream>>>(
        flag, h2, upw, 0, 2048, a, a, 4096, 2048);
    gemm_bt<DT, DT, 1, 1, 1><<<dim3(32, 16), 256, 0, stream>>>(
        flag, a, downw, 0, 8192, x2, x2, 2048, 4096);
    // chunk 1
    gemm_bt<DT, DT, 1, 1, 2><<<dim3(32, 32), 256, 0, stream>>>(
        flag, h2, gatew, (size_t)4096 * 2048, 2048, nullptr, a, 4096, 2048);
    gemm_bt<DT, DT, 1, 1, 3><<<dim3(32, 32), 256, 0, stream>>>(
        flag, h2, upw, (size_t)4096 * 2048, 2048, a, a, 4096, 2048);
    gemm_bt<DT, DT, 1, DT, 1><<<dim3(32, 16), 256, 0, stream>>>(
        flag, a, downw, 4096, 8192, x2, outp, 2048, 4096);
}

extern "C" void kernel_launch(void* const* d_in, const int* in_sizes, int n_in,
                              void* d_out, int out_size, void* d_ws, size_t ws_size,
                              hipStream_t stream)
{
    const void* x      = d_in[0];
    // d_in[1] = causal mask: implemented analytically, unused
    const void* n1w    = d_in[2];
    const void* qkv_w  = d_in[3];
    const void* out_w  = d_in[4];
    const void* n2w    = d_in[5];
    const void* gate_w = d_in[6];
    const void* up_w   = d_in[7];
    const void* down_w = d_in[8];

    char* ws = (char*)d_ws;
    const size_t MB = 1024 * 1024;
    size_t flag_off = 64 * MB;
    if (ws_size < flag_off + 4) flag_off = (ws_size - 4) & ~(size_t)3;
    int* flag = (int*)(ws + flag_off);

    detect_kernel<<<1, 256, 0, stream>>>((const unsigned int*)x, flag);
    run_pipeline<0>(x, n1w, qkv_w, out_w, n2w, gate_w, up_w, down_w,
                    d_out, ws, flag, stream);
    run_pipeline<1>(x, n1w, qkv_w, out_w, n2w, gate_w, up_w, down_w,
                    d_out, ws, flag, stream);
}

// Round 5
// 1287.462 us; speedup vs baseline: 2.4080x; 1.0022x over previous
//
#include <hip/hip_runtime.h>

// ---------------------------------------------------------------------------
// TransformerBlock: B=2, L=2048, D=2048, H=16, HD=128, FF=8192.
// Dual-dtype (runtime-detected): DT=0 (f32 I/O) and DT=1 (bf16 I/O) pipelines;
// detector writes flag; kernels no-op unless flag==PID. Intermediates bf16.
// Active path in harness: DT=1 (verified: output read as bf16 and passing).
// DT=1 GEMMs use gemm8: 256x256 8-phase-style schedule (BK=64, 8 waves,
// double-buffered 128KiB LDS, counted-vmcnt staging, raw barriers, setprio).
// DT=0 keeps the proven 128x128 gemm_bt.
// Workspace (64MB + flag word): qkv[0,48) / x2[0,16) / h2[16,32) / a[32,64)
//   h,o[48,64); flag at min(64MB, ws_size-4)
// ---------------------------------------------------------------------------

typedef __attribute__((ext_vector_type(8))) short bf16x8;
typedef __attribute__((ext_vector_type(4))) float f32x4;

__device__ __forceinline__ float b2f(unsigned short u) {
    return __uint_as_float(((unsigned int)u) << 16);
}
__device__ __forceinline__ unsigned short f2b(float f) {
    unsigned int i = __float_as_uint(f);
    i += 0x7fffu + ((i >> 16) & 1u);   // RNE
    return (unsigned short)(i >> 16);
}
// packed f32x2 -> bf16x2 (RNE), single VALU op; no builtin on gfx950
__device__ __forceinline__ unsigned int cvt_pk_bf16(float lo, float hi) {
    unsigned int r;
    asm("v_cvt_pk_bf16_f32 %0, %1, %2" : "=v"(r) : "v"(lo), "v"(hi));
    return r;
}

// async global->LDS, 16 B per lane; LDS dest is wave-uniform base + lane*16.
__device__ __forceinline__ void gload_lds16(const unsigned short* g, unsigned short* l) {
    __builtin_amdgcn_global_load_lds(
        (const __attribute__((address_space(1))) unsigned int*)g,
        (__attribute__((address_space(3))) unsigned int*)l,
        16, 0, 0);
}

// ---- typed I/O helpers: DT=1 bf16, DT=0 f32 -------------------------------
template<int DT> struct IO;
template<> struct IO<1> {
    static __device__ __forceinline__ void load8(const void* p, size_t i, float* o) {
        uint4 v = *(const uint4*)((const unsigned short*)p + i);
        const unsigned short* u = (const unsigned short*)&v;
#pragma unroll
        for (int e = 0; e < 8; e++) o[e] = b2f(u[e]);
    }
    static __device__ __forceinline__ float load1(const void* p, size_t i) {
        return b2f(((const unsigned short*)p)[i]);
    }
    static __device__ __forceinline__ void store1(void* p, size_t i, float v) {
        ((unsigned short*)p)[i] = f2b(v);
    }
};
template<> struct IO<0> {
    static __device__ __forceinline__ void load8(const void* p, size_t i, float* o) {
        float4 a = *(const float4*)((const float*)p + i);
        float4 b = *(const float4*)((const float*)p + i + 4);
        o[0]=a.x; o[1]=a.y; o[2]=a.z; o[3]=a.w;
        o[4]=b.x; o[5]=b.y; o[6]=b.z; o[7]=b.w;
    }
    static __device__ __forceinline__ float load1(const void* p, size_t i) {
        return ((const float*)p)[i];
    }
    static __device__ __forceinline__ void store1(void* p, size_t i, float v) {
        ((float*)p)[i] = v;
    }
};

// ---------------------------------------------------------------------------
// Detector: classify x's encoding. flag = 1 (bf16) / 0 (f32).
// ---------------------------------------------------------------------------
__global__ __launch_bounds__(256) void detect_kernel(
    const unsigned int* __restrict__ x, int* __restrict__ flag)
{
    const int t = threadIdx.x;
    int cnt = 0;
    for (int i = t; i < 2048; i += 256) {
        unsigned int e = (x[i] >> 7) & 0xFFu;
        cnt += (e >= 100u && e <= 140u) ? 1 : 0;
    }
#pragma unroll
    for (int off = 32; off; off >>= 1) cnt += __shfl_xor(cnt, off);
    __shared__ int red[4];
    if ((t & 63) == 0) red[t >> 6] = cnt;
    __syncthreads();
    if (t == 0) {
        int tot = red[0] + red[1] + red[2] + red[3];
        flag[0] = (2 * tot > 2048) ? 1 : 0;
    }
}

// ---------------------------------------------------------------------------
// RMSNorm row kernel. X dtype DTX, weight DTW, output always bf16.
// ---------------------------------------------------------------------------
template<int PID, int DTX, int DTW>
__global__ __launch_bounds__(256) void rmsnorm_kernel(
    const int* __restrict__ flag,
    const void* __restrict__ X,
    const void* __restrict__ Wn,
    unsigned short* __restrict__ Out)
{
    if (flag[0] != PID) return;
    const int row = blockIdx.x, t = threadIdx.x;
    float xf[8];
    IO<DTX>::load8(X, (size_t)row * 2048 + t * 8, xf);
    float ss = 0.f;
#pragma unroll
    for (int e = 0; e < 8; e++) ss += xf[e] * xf[e];
#pragma unroll
    for (int off = 32; off; off >>= 1) ss += __shfl_xor(ss, off);
    __shared__ float red[4];
    if ((t & 63) == 0) red[t >> 6] = ss;
    __syncthreads();
    float rr = rsqrtf((red[0] + red[1] + red[2] + red[3]) * (1.0f / 2048.0f) + 1e-6f);
    float wf[8];
    IO<DTW>::load8(Wn, (size_t)t * 8, wf);
    float y[8];
#pragma unroll
    for (int e = 0; e < 8; e++) y[e] = xf[e] * rr * wf[e];
    uint4 ov;
    ov.x = cvt_pk_bf16(y[0], y[1]);
    ov.y = cvt_pk_bf16(y[2], y[3]);
    ov.z = cvt_pk_bf16(y[4], y[5]);
    ov.w = cvt_pk_bf16(y[6], y[7]);
    *(uint4*)(Out + (size_t)row * 2048 + t * 8) = ov;
}

// ---------------------------------------------------------------------------
// gemm8: 256x256 tile, BK=64, 8 waves (512 thr) as 2M x 4N; per-wave 128x64.
// Double-buffered LDS [2][256][64] bf16 per matrix = 128 KiB total, XOR
// swizzle at 16B granules (slot s of row r holds granule s^(r&7)).
// Per K-tile: 4 quadrant phases {ds_read frags; setprio(1); 16 MFMA;
// setprio(0); s_barrier}. Staging for tile T+1 issued in phases 0 (A) and
// 1 (B) into buf^1; single s_waitcnt vmcnt(0) at end of phase 3 (~3 phases
// after issue -> HBM latency covered); raw barriers, no per-phase drain.
// All I/O bf16 (DT=1 pipeline only). EPI: 0=store 1=+Res 2=silu 3=*Res.
// ---------------------------------------------------------------------------
#define TBM 256
#define TBN 256
#define TBK 64

template<int PID, int EPI>
__global__ __launch_bounds__(512, 2) void gemm8(
    const int* __restrict__ flag,
    const unsigned short* __restrict__ A,
    const unsigned short* __restrict__ W, size_t woff, int ldw,
    const unsigned short* __restrict__ Res,
    unsigned short* __restrict__ C,
    int N, int K, int gx)
{
    if (flag[0] != PID) return;
    __shared__ unsigned short sA[2][TBM * TBK];
    __shared__ unsigned short sB[2][TBN * TBK];

    const int t = threadIdx.x;
    // bijective XCD swizzle (m204): contiguous swz chunk per XCD
    const int nwg = gridDim.x;
    const int q8 = nwg >> 3, r8 = nwg & 7;
    const int xcd = blockIdx.x & 7, o = blockIdx.x >> 3;
    const int swz = (xcd < r8 ? xcd * (q8 + 1) : r8 * (q8 + 1) + (xcd - r8) * q8) + o;
    const int bm = (swz % gx) * TBM;
    const int bn = (swz / gx) * TBN;

    const int w = t >> 6, lane = t & 63, quad = lane >> 4, l16 = lane & 15;
    const int wr = w >> 2, wc = w & 3;
    const int sg = (lane & 7) ^ (lane >> 3);      // pre-swizzled source granule

    const unsigned short* Ab = A + (size_t)(bm + w * 8 + (lane >> 3)) * K + sg * 8;
    const unsigned short* Wb = W + woff + (size_t)(bn + w * 8 + (lane >> 3)) * ldw + sg * 8;
    const int dstb = (w * 8) * TBK;               // wave-uniform LDS row base

    f32x4 acc[8][4];
#pragma unroll
    for (int mi = 0; mi < 8; mi++)
#pragma unroll
        for (int ni = 0; ni < 4; ni++) {
            f32x4 z = {0.f, 0.f, 0.f, 0.f};
            acc[mi][ni] = z;
        }

#define STAGE_A8(b, k0)                                                        \
    {                                                                          \
        _Pragma("unroll")                                                      \
        for (int i = 0; i < 4; i++)                                            \
            gload_lds16(Ab + (size_t)(i * 64) * K + (k0),                      \
                        &sA[b][i * 64 * TBK + dstb]);                          \
    }
#define STAGE_B8(b, k0)                                                        \
    {                                                                          \
        _Pragma("unroll")                                                      \
        for (int i = 0; i < 4; i++)                                            \
            gload_lds16(Wb + (size_t)(i * 64) * ldw + (k0),                    \
                        &sB[b][i * 64 * TBK + dstb]);                          \
    }

    // prologue: stage tile 0 -> buf 0
    STAGE_A8(0, 0)
    STAGE_B8(0, 0)
    asm volatile("s_waitcnt vmcnt(0)" ::: "memory");
    asm volatile("s_barrier" ::: "memory");

    const int NT = K / TBK;
    bf16x8 bfr[4][2];

    for (int T = 0; T < NT; T++) {
        const int buf = T & 1;
        const int k0n = (T + 1) * TBK;
        const bool more = (T + 1 < NT);

        // ---- phase 0: stage A[T+1]; read B-frags (8) + A-quad0 (4); 16 MFMA
        if (more) STAGE_A8(buf ^ 1, k0n)
#pragma unroll
        for (int ni = 0; ni < 4; ni++) {
            const int row = wc * 64 + ni * 16 + l16;
#pragma unroll
            for (int ks = 0; ks < 2; ks++)
                bfr[ni][ks] = *(const bf16x8*)
                    &sB[buf][row * TBK + (((ks * 4 + quad) ^ (row & 7)) * 8)];
        }
        {
            bf16x8 af[2][2];
#pragma unroll
            for (int m2 = 0; m2 < 2; m2++) {
                const int row = wr * 128 + (0 + m2) * 16 + l16;
#pragma unroll
                for (int ks = 0; ks < 2; ks++)
                    af[m2][ks] = *(const bf16x8*)
                        &sA[buf][row * TBK + (((ks * 4 + quad) ^ (row & 7)) * 8)];
            }
            __builtin_amdgcn_s_setprio(1);
#pragma unroll
            for (int m2 = 0; m2 < 2; m2++)
#pragma unroll
                for (int ks = 0; ks < 2; ks++)
#pragma unroll
                    for (int ni = 0; ni < 4; ni++)
                        acc[0 + m2][ni] = __builtin_amdgcn_mfma_f32_16x16x32_bf16(
                            af[m2][ks], bfr[ni][ks], acc[0 + m2][ni], 0, 0, 0);
            __builtin_amdgcn_s_setprio(0);
        }
        asm volatile("s_barrier" ::: "memory");

        // ---- phase 1: stage B[T+1]; A-quad1; 16 MFMA
        if (more) STAGE_B8(buf ^ 1, k0n)
        {
            bf16x8 af[2][2];
#pragma unroll
            for (int m2 = 0; m2 < 2; m2++) {
                const int row = wr * 128 + (2 + m2) * 16 + l16;
#pragma unroll
                for (int ks = 0; ks < 2; ks++)
                    af[m2][ks] = *(const bf16x8*)
                        &sA[buf][row * TBK + (((ks * 4 + quad) ^ (row & 7)) * 8)];
            }
            __builtin_amdgcn_s_setprio(1);
#pragma unroll
            for (int m2 = 0; m2 < 2; m2++)
#pragma unroll
                for (int ks = 0; ks < 2; ks++)
#pragma unroll
                    for (int ni = 0; ni < 4; ni++)
                        acc[2 + m2][ni] = __builtin_amdgcn_mfma_f32_16x16x32_bf16(
                            af[m2][ks], bfr[ni][ks], acc[2 + m2][ni], 0, 0, 0);
            __builtin_amdgcn_s_setprio(0);
        }
        asm volatile("s_barrier" ::: "memory");

        // ---- phase 2: A-quad2; 16 MFMA
        {
            bf16x8 af[2][2];
#pragma unroll
            for (int m2 = 0; m2 < 2; m2++) {
                const int row = wr * 128 + (4 + m2) * 16 + l16;
#pragma unroll
                for (int ks = 0; ks < 2; ks++)
                    af[m2][ks] = *(const bf16x8*)
                        &sA[buf][row * TBK + (((ks * 4 + quad) ^ (row & 7)) * 8)];
            }
            __builtin_amdgcn_s_setprio(1);
#pragma unroll
            for (int m2 = 0; m2 < 2; m2++)
#pragma unroll
                for (int ks = 0; ks < 2; ks++)
#pragma unroll
                    for (int ni = 0; ni < 4; ni++)
                        acc[4 + m2][ni] = __builtin_amdgcn_mfma_f32_16x16x32_bf16(
                            af[m2][ks], bfr[ni][ks], acc[4 + m2][ni], 0, 0, 0);
            __builtin_amdgcn_s_setprio(0);
        }
        asm volatile("s_barrier" ::: "memory");

        // ---- phase 3: A-quad3; 16 MFMA; drain staging; flip
        {
            bf16x8 af[2][2];
#pragma unroll
            for (int m2 = 0; m2 < 2; m2++) {
                const int row = wr * 128 + (6 + m2) * 16 + l16;
#pragma unroll
                for (int ks = 0; ks < 2; ks++)
                    af[m2][ks] = *(const bf16x8*)
                        &sA[buf][row * TBK + (((ks * 4 + quad) ^ (row & 7)) * 8)];
            }
            __builtin_amdgcn_s_setprio(1);
#pragma unroll
            for (int m2 = 0; m2 < 2; m2++)
#pragma unroll
                for (int ks = 0; ks < 2; ks++)
#pragma unroll
                    for (int ni = 0; ni < 4; ni++)
                        acc[6 + m2][ni] = __builtin_amdgcn_mfma_f32_16x16x32_bf16(
                            af[m2][ks], bfr[ni][ks], acc[6 + m2][ni], 0, 0, 0);
            __builtin_amdgcn_s_setprio(0);
        }
        asm volatile("s_waitcnt vmcnt(0)" ::: "memory");
        asm volatile("s_barrier" ::: "memory");
    }
#undef STAGE_A8
#undef STAGE_B8

    // ---- epilogue ----
#pragma unroll
    for (int mi = 0; mi < 8; mi++)
#pragma unroll
        for (int ni = 0; ni < 4; ni++)
#pragma unroll
            for (int r = 0; r < 4; r++) {
                const int row = bm + wr * 128 + mi * 16 + quad * 4 + r;
                const int col = bn + wc * 64 + ni * 16 + l16;
                const size_t idx = (size_t)row * N + col;
                float v = acc[mi][ni][r];
                if constexpr (EPI == 1) v += b2f(Res[idx]);
                if constexpr (EPI == 2) v = v / (1.f + __expf(-v));
                if constexpr (EPI == 3) v *= b2f(Res[idx]);
                C[idx] = f2b(v);
            }
}

// ---------------------------------------------------------------------------
// GEMM 128x128 (proven round-3/4 kernel) — used by the DT=0 pipeline.
// ---------------------------------------------------------------------------
#define BM 128
#define BN 128
#define BKK 64

template<int PID, int DTW, int DTR, int DTC, int EPI>
__global__ __launch_bounds__(256) void gemm_bt(
    const int* __restrict__ flag,
    const unsigned short* __restrict__ A,
    const void* __restrict__ W, size_t woff, int ldw,
    const void* __restrict__ Res,
    void* __restrict__ C,
    int N, int K)
{
    if (flag[0] != PID) return;
    __shared__ unsigned short sA[BM * BKK];
    __shared__ unsigned short sB[BN * BKK];
    const int t = threadIdx.x;
    const int bm = blockIdx.x * BM, bn = blockIdx.y * BN;
    const int w = t >> 6, lane = t & 63, quad = lane >> 4, l16 = lane & 15;
    const int wm = (w & 1) * 64, wn = (w >> 1) * 64;

    const int srow = lane >> 3;
    const int sg   = (lane & 7) ^ srow;

    f32x4 acc[4][4];
#pragma unroll
    for (int mi = 0; mi < 4; mi++)
#pragma unroll
        for (int ni = 0; ni < 4; ni++) {
            f32x4 z = {0.f, 0.f, 0.f, 0.f};
            acc[mi][ni] = z;
        }

    const unsigned short* Ap = A;
    for (int k0 = 0; k0 < K; k0 += BKK) {
#pragma unroll
        for (int i = 0; i < 4; i++) {
            const int r0 = w * 32 + i * 8;
            gload_lds16(Ap + (size_t)(bm + r0 + srow) * K + k0 + sg * 8,
                        &sA[r0 * BKK]);
        }
        if constexpr (DTW == 1) {
#pragma unroll
            for (int i = 0; i < 4; i++) {
                const int r0 = w * 32 + i * 8;
                gload_lds16((const unsigned short*)W + woff +
                                (size_t)(bn + r0 + srow) * ldw + k0 + sg * 8,
                            &sB[r0 * BKK]);
            }
        } else {
#pragma unroll
            for (int i = 0; i < 4; i++) {
                const int r0 = w * 32 + i * 8;
                const int r = r0 + srow;
                const float* gp = (const float*)W + woff +
                                  (size_t)(bn + r) * ldw + k0 + (lane & 7) * 8;
                float4 f0 = *(const float4*)gp;
                float4 f1 = *(const float4*)(gp + 4);
                uint4 wb;
                wb.x = cvt_pk_bf16(f0.x, f0.y);
                wb.y = cvt_pk_bf16(f0.z, f0.w);
                wb.z = cvt_pk_bf16(f1.x, f1.y);
                wb.w = cvt_pk_bf16(f1.z, f1.w);
                *(uint4*)&sB[r * BKK + (((lane & 7) ^ (r & 7)) * 8)] = wb;
            }
        }
        __syncthreads();

#pragma unroll
        for (int ks = 0; ks < 2; ks++) {
            bf16x8 af[4], bfr[4];
#pragma unroll
            for (int mi = 0; mi < 4; mi++) {
                const int r = wm + mi * 16 + l16;
                af[mi] = *(const bf16x8*)
                    &sA[r * BKK + (((ks * 4 + quad) ^ (r & 7)) * 8)];
            }
#pragma unroll
            for (int ni = 0; ni < 4; ni++) {
                const int r = wn + ni * 16 + l16;
                bfr[ni] = *(const bf16x8*)
                    &sB[r * BKK + (((ks * 4 + quad) ^ (r & 7)) * 8)];
            }
#pragma unroll
            for (int mi = 0; mi < 4; mi++)
#pragma unroll
                for (int ni = 0; ni < 4; ni++)
                    acc[mi][ni] = __builtin_amdgcn_mfma_f32_16x16x32_bf16(
                        af[mi], bfr[ni], acc[mi][ni], 0, 0, 0);
        }
        __syncthreads();
    }

#pragma unroll
    for (int mi = 0; mi < 4; mi++)
#pragma unroll
        for (int ni = 0; ni < 4; ni++)
#pragma unroll
            for (int r = 0; r < 4; r++) {
                const int row = bm + wm + mi * 16 + quad * 4 + r;
                const int col = bn + wn + ni * 16 + l16;
                const size_t idx = (size_t)row * N + col;
                float v = acc[mi][ni][r];
                if constexpr (EPI == 1) v += IO<DTR>::load1(Res, idx);
                if constexpr (EPI == 2) v = v / (1.f + __expf(-v));
                if constexpr (EPI == 3) v *= IO<DTR>::load1(Res, idx);
                IO<DTC>::store1(C, idx, v);
            }
}

// ---------------------------------------------------------------------------
// Flash-style MFMA attention (unchanged from passing round-2 version).
// ---------------------------------------------------------------------------
__device__ __forceinline__ int vt_idx(int d, int kv) {
    return d * 72 + (kv ^ (d & 56));
}

template<int PID>
__global__ __launch_bounds__(256) void attn_kernel(
    const int* __restrict__ flag,
    const unsigned short* __restrict__ QKV,
    unsigned short* __restrict__ O)
{
    if (flag[0] != PID) return;
    __shared__ unsigned short sK[64 * 128];
    __shared__ unsigned short sVt[9280];
    __shared__ unsigned short sP[4][16 * 72];

    const int t = threadIdx.x;
    const int bh = blockIdx.x >> 4;
    const int jj = blockIdx.x & 15;
    const int b = bh >> 4, hh = bh & 15;
    const int w = t >> 6, lane = t & 63, quad = lane >> 4, l16 = lane & 15;

    const unsigned short* Qb = QKV + (size_t)(b * 2048) * 6144 + hh * 128;
    const unsigned short* Kb = Qb + 2048;
    const unsigned short* Vb = Qb + 4096;

    const int str = t >> 4;
    const int stc = (t & 15) * 8;

#pragma unroll
    for (int half = 0; half < 2; half++) {
        const int qt = half ? (31 - jj) : jj;
        const int qbase = qt * 64;

        bf16x8 qf[4];
        {
            const unsigned short* qp = Qb + (size_t)(qbase + w * 16 + l16) * 6144;
#pragma unroll
            for (int ks = 0; ks < 4; ks++)
                qf[ks] = *(const bf16x8*)(qp + ks * 32 + quad * 8);
        }

        float m[4], l[4];
#pragma unroll
        for (int r = 0; r < 4; r++) { m[r] = -1e30f; l[r] = 0.f; }
        f32x4 accO[8];
#pragma unroll
        for (int d0 = 0; d0 < 8; d0++) {
            f32x4 z = {0.f, 0.f, 0.f, 0.f};
            accO[d0] = z;
        }

        for (int tk = 0; tk <= qt; tk++) {
            const int kv0 = tk * 64;
            __syncthreads();
#pragma unroll
            for (int pass = 0; pass < 4; pass++) {
                const int rr = str + pass * 16;
                uint4 kv4 = *(const uint4*)(Kb + (size_t)(kv0 + rr) * 6144 + stc);
                *(uint4*)&sK[(rr * 128 + stc) ^ ((rr & 7) << 3)] = kv4;
                uint4 vv4 = *(const uint4*)(Vb + (size_t)(kv0 + rr) * 6144 + stc);
                const unsigned short* vu = (const unsigned short*)&vv4;
#pragma unroll
                for (int e = 0; e < 8; e++)
                    sVt[vt_idx(stc + e, rr)] = vu[e];
            }
            __syncthreads();

            const bool diag = (tk == qt);
            f32x4 s[4];
#pragma unroll
            for (int nf = 0; nf < 4; nf++) {
                f32x4 z = {0.f, 0.f, 0.f, 0.f};
                s[nf] = z;
                if (!(diag && nf > w)) {
#pragma unroll
                    for (int ks = 0; ks < 4; ks++) {
                        const int row = nf * 16 + l16;
                        bf16x8 kf = *(const bf16x8*)
                            &sK[(row * 128 + ks * 32 + quad * 8) ^ ((row & 7) << 3)];
                        s[nf] = __builtin_amdgcn_mfma_f32_16x16x32_bf16(qf[ks], kf, s[nf], 0, 0, 0);
                    }
                }
#pragma unroll
                for (int r = 0; r < 4; r++) s[nf][r] *= 0.08838834764831845f;
            }
            if (diag) {
#pragma unroll
                for (int nf = 0; nf < 4; nf++)
#pragma unroll
                    for (int r = 0; r < 4; r++)
                        if (nf * 16 + l16 > w * 16 + quad * 4 + r) s[nf][r] = -1e30f;
            }

            float alpha[4], rs[4];
#pragma unroll
            for (int r = 0; r < 4; r++) {
                float v = fmaxf(fmaxf(s[0][r], s[1][r]), fmaxf(s[2][r], s[3][r]));
                v = fmaxf(v, __shfl_xor(v, 1));
                v = fmaxf(v, __shfl_xor(v, 2));
                v = fmaxf(v, __shfl_xor(v, 4));
                v = fmaxf(v, __shfl_xor(v, 8));
                float mn = fmaxf(m[r], v);
                alpha[r] = __expf(m[r] - mn);
                m[r] = mn;
                rs[r] = 0.f;
            }
#pragma unroll
            for (int nf = 0; nf < 4; nf++)
#pragma unroll
                for (int r = 0; r < 4; r++) {
                    float p = __expf(s[nf][r] - m[r]);
                    rs[r] += p;
                    sP[w][(quad * 4 + r) * 72 + nf * 16 + l16] = f2b(p);
                }
#pragma unroll
            for (int r = 0; r < 4; r++) {
                float sum = rs[r];
                sum += __shfl_xor(sum, 1);
                sum += __shfl_xor(sum, 2);
                sum += __shfl_xor(sum, 4);
                sum += __shfl_xor(sum, 8);
                l[r] = l[r] * alpha[r] + sum;
            }
#pragma unroll
            for (int d0 = 0; d0 < 8; d0++)
#pragma unroll
                for (int r = 0; r < 4; r++) accO[d0][r] *= alpha[r];

#pragma unroll
            for (int ks = 0; ks < 2; ks++) {
                bf16x8 pa = *(const bf16x8*)&sP[w][l16 * 72 + ks * 32 + quad * 8];
#pragma unroll
                for (int d0 = 0; d0 < 8; d0++) {
                    bf16x8 vb = *(const bf16x8*)
                        &sVt[vt_idx(d0 * 16 + l16, ks * 32 + quad * 8)];
                    accO[d0] = __builtin_amdgcn_mfma_f32_16x16x32_bf16(pa, vb, accO[d0], 0, 0, 0);
                }
            }
        }

        float linv[4];
#pragma unroll
        for (int r = 0; r < 4; r++) linv[r] = 1.0f / l[r];
        unsigned short* Op = O + (size_t)(b * 2048 + qbase + w * 16) * 2048 + hh * 128;
#pragma unroll
        for (int d0 = 0; d0 < 8; d0++)
#pragma unroll
            for (int r = 0; r < 4; r++)
                Op[(size_t)(quad * 4 + r) * 2048 + d0 * 16 + l16] =
                    f2b(accO[d0][r] * linv[r]);
    }
}

// ---------------------------------------------------------------------------
template<int DT>
static void run_pipeline(const void* x, const void* n1w, const void* qkvw,
                         const void* outw, const void* n2w, const void* gatew,
                         const void* upw, const void* downw,
                         void* outp, char* ws, const int* flag, hipStream_t stream)
{
    const size_t MB = 1024 * 1024;
    unsigned short* qkv = (unsigned short*)(ws);            // [0,48)
    unsigned short* x2  = (unsigned short*)(ws);            // [0,16) after qkv dead
    unsigned short* h2  = (unsigned short*)(ws + 16 * MB);  // [16,32)
    unsigned short* a   = (unsigned short*)(ws + 32 * MB);  // [32,64)
    unsigned short* h   = (unsigned short*)(ws + 48 * MB);  // [48,64)
    unsigned short* o   = (unsigned short*)(ws + 48 * MB);  // [48,64) after h dead

    // 1) h = rmsnorm(x, w1)
    rmsnorm_kernel<DT, DT, DT><<<4096, 256, 0, stream>>>(flag, x, n1w, h);

    if constexpr (DT == 1) {
        const unsigned short* Wq = (const unsigned short*)qkvw;
        const unsigned short* Wo = (const unsigned short*)outw;
        const unsigned short* Wg = (const unsigned short*)gatew;
        const unsigned short* Wu = (const unsigned short*)upw;
        const unsigned short* Wd = (const unsigned short*)downw;
        // 2) qkv = h @ qkv_w^T  (M=4096 N=6144 K=2048): 16x24 tiles
        gemm8<1, 0><<<384, 512, 0, stream>>>(
            flag, h, Wq, 0, 2048, nullptr, qkv, 6144, 2048, 16);
        // 3) attention -> o
        attn_kernel<1><<<512, 256, 0, stream>>>(flag, qkv, o);
        // 4) x2 = x + o @ out_w^T  (N=2048): 16x8 tiles
        gemm8<1, 1><<<128, 512, 0, stream>>>(
            flag, o, Wo, 0, 2048, (const unsigned short*)x, x2, 2048, 2048, 16);
        // 5) h2 = rmsnorm(x2, w2)
        rmsnorm_kernel<1, 1, 1><<<4096, 256, 0, stream>>>(flag, x2, n2w, h2);
        // 6-11) FF, two chunks of 4096 FF-cols
        gemm8<1, 2><<<256, 512, 0, stream>>>(
            flag, h2, Wg, 0, 2048, nullptr, a, 4096, 2048, 16);
        gemm8<1, 3><<<256, 512, 0, stream>>>(
            flag, h2, Wu, 0, 2048, a, a, 4096, 2048, 16);
        gemm8<1, 1><<<128, 512, 0, stream>>>(
            flag, a, Wd, 0, 8192, x2, x2, 2048, 4096, 16);
        gemm8<1, 2><<<256, 512, 0, stream>>>(
            flag, h2, Wg, (size_t)4096 * 2048, 2048, nullptr, a, 4096, 2048, 16);
        gemm8<1, 3><<<256, 512, 0, stream>>>(
            flag, h2, Wu, (size_t)4096 * 2048, 2048, a, a, 4096, 2048, 16);
        gemm8<1, 1><<<128, 512, 0, stream>>>(
            flag, a, Wd, 4096, 8192, x2, (unsigned short*)outp, 2048, 4096, 16);
    } else {
        // DT=0 fallback pipeline (proven 128x128 kernels)
        gemm_bt<0, 0, 1, 1, 0><<<dim3(32, 48), 256, 0, stream>>>(
            flag, h, qkvw, 0, 2048, nullptr, qkv, 6144, 2048);
        attn_kernel<0><<<512, 256, 0, stream>>>(flag, qkv, o);
        gemm_bt<0, 0, 0, 1, 1><<<dim3(32, 16), 256, 0, stream>>>(
            flag, o, outw, 0, 2048, x, x2, 2048, 2048);
        rmsnorm_kernel<0, 1, 0><<<4096, 256, 0, stream>>>(flag, x2, n2w, h2);
        gemm_bt<0, 0, 1, 1, 2><<<dim3(32, 32), 256, 0, stream>>>(
            flag, h2, gatew, 0, 2048, nullptr, a, 4096, 2048);
        gemm_bt<0, 0, 1, 1, 3><<<dim3(32, 32), 256, 0, stream>>>(
            flag, h2, upw, 0, 2048, a, a, 4096, 2048);
        gemm_bt<0, 0, 1, 1, 1><<<dim3(32, 16), 256, 0, stream>>>(
            flag, a, downw, 0, 8192, x2, x2, 2048, 4096);
        gemm_bt<0, 0, 1, 1, 2><<<dim3(32, 32), 256, 0, stream>>>(
            flag, h2, gatew, (size_t)4096 * 2048, 2048, nullptr, a, 4096, 2048);
        gemm_bt<0, 0, 1, 1, 3><<<dim3(32, 32), 256, 0, stream>>>(
            flag, h2, upw, (size_t)4096 * 2048, 2048, a, a, 4096, 2048);
        gemm_bt<0, 0, 1, 0, 1><<<dim3(32, 16), 256, 0, stream>>>(
            flag, a, downw, 4096, 8192, x2, outp, 2048, 4096);
    }
}

extern "C" void kernel_launch(void* const* d_in, const int* in_sizes, int n_in,
                              void* d_out, int out_size, void* d_ws, size_t ws_size,
                              hipStream_t stream)
{
    const void* x      = d_in[0];
    // d_in[1] = causal mask: implemented analytically, unused
    const void* n1w    = d_in[2];
    const void* qkv_w  = d_in[3];
    const void* out_w  = d_in[4];
    const void* n2w    = d_in[5];
    const void* gate_w = d_in[6];
    const void* up_w   = d_in[7];
    const void* down_w = d_in[8];

    char* ws = (char*)d_ws;
    const size_t MB = 1024 * 1024;
    size_t flag_off = 64 * MB;
    if (ws_size < flag_off + 4) flag_off = (ws_size - 4) & ~(size_t)3;
    int* flag = (int*)(ws + flag_off);

    detect_kernel<<<1, 256, 0, stream>>>((const unsigned int*)x, flag);
    run_pipeline<0>(x, n1w, qkv_w, out_w, n2w, gate_w, up_w, down_w,
                    d_out, ws, flag, stream);
    run_pipeline<1>(x, n1w, qkv_w, out_w, n2w, gate_w, up_w, down_w,
                    d_out, ws, flag, stream);
}